// Round 1
// baseline (686.551 us; speedup 1.0000x reference)
//
#include <hip/hip_runtime.h>

typedef unsigned short u16;
typedef unsigned int   u32;
typedef __bf16 bf16x8 __attribute__((ext_vector_type(8)));
typedef float  f32x4  __attribute__((ext_vector_type(4)));

#define M_ROWS 50000
#define M_PAD  50048
#define M_TILES 391
#define N_COLS 1350
#define N_PAD  1408
#define N_TILES 11
#define K_DIM  300
#define K_PAD  320
#define KT_HALF 10
#define KT_TOT  20      // hi/lo split: K = 640
#define TROW   1408

static __device__ __forceinline__ u16 f2bf(float x){
  union { float f; u32 u; } a; a.f = x;
  u32 r = a.u + 0x7fffu + ((a.u >> 16) & 1u);   // RNE
  return (u16)(r >> 16);
}
static __device__ __forceinline__ float bf2f(u16 h){
  union { u32 u; float f; } a; a.u = ((u32)h) << 16; return a.f;
}

// ---------------- K1a: embedding -> swizzled bf16 hi/lo A ----------------
// A layout: [tile_m(391)][kt(20)][8192B]; within 8KB tile, element (m_local,k_local):
//   off_u16 = mb*512 + kg*128 + row*8 + k8   (mb=m_local/16,row=m_local%16,kg=k_local/8,k8=k_local%8)
// -> LDS chunk at lane*16B is exactly one MFMA A-fragment (A[m=lane&15][k=quad*8+j]).
__global__ void build_A(const float* __restrict__ emb, u16* __restrict__ A){
  int t = blockIdx.x * 256 + threadIdx.x;
  if (t >= M_PAD * 80) return;
  int m = t / 80, kg_all = t % 80;
  int half = (kg_all >= 40) ? 1 : 0;
  int kgh = kg_all - half * 40;               // 0..39 within half
  int k0 = kgh * 8;
  int kt = half * KT_HALF + (kgh >> 2);
  int kgl = kgh & 3;
  int tile = m >> 7, ml = m & 127, mb = ml >> 4, row = ml & 15;
  size_t off = ((size_t)tile * KT_TOT + kt) * 4096 + mb * 512 + kgl * 128 + row * 8;
  union { uint4 q; u16 s[8]; } p;
  #pragma unroll
  for (int j = 0; j < 8; ++j){
    int k = k0 + j;
    float x = 0.f;
    if (m < M_ROWS && k < K_DIM){
      float e = emb[(size_t)m * K_DIM + k];
      u16 hi = f2bf(e);
      x = half ? (e - bf2f(hi)) : bf2f(hi);
    }
    p.s[j] = f2bf(x);
  }
  *(uint4*)(A + off) = p.q;
}

// ---------------- K1b: w1/w2/w3 -> swizzled bf16 B (duplicated for hi/lo) --------
// Logical B^T[n][k]: n = br*450 + tap*150 + f, value = w_br[tap][k][f]; k halves identical.
__global__ void build_B(const float* __restrict__ w1, const float* __restrict__ w2,
                        const float* __restrict__ w3, u16* __restrict__ B){
  int t = blockIdx.x * 256 + threadIdx.x;
  if (t >= N_PAD * 640) return;
  int n = t / 640, k = t % 640;
  int kk = k % K_PAD;
  float x = 0.f;
  if (n < N_COLS && kk < K_DIM){
    int br = n / 450, rem = n % 450, tap = rem / 150, f = rem % 150;
    const float* w = (br == 0) ? w1 : ((br == 1) ? w2 : w3);
    x = w[(tap * K_DIM + kk) * 150 + f];
  }
  int tn = n >> 7, nl = n & 127, nb = nl >> 4, col = nl & 15;
  int kt = k >> 5, kl = k & 31, kg = kl >> 3, k8 = kl & 7;
  B[((size_t)tn * KT_TOT + kt) * 4096 + nb * 512 + kg * 128 + col * 8 + k8] = f2bf(x);
}

// ---------------- K2: T = A x B^T  (m97-style 128x128 tile, BK=32) ----------------
__global__ __launch_bounds__(256) void gemm_k(const u16* __restrict__ A, const u16* __restrict__ B,
                                              u16* __restrict__ T){
  __shared__ __align__(16) u16 lds[8192];   // A tile 8KB | B tile 8KB
  const int tm = blockIdx.x, tn = blockIdx.y;
  const int tid = threadIdx.x, wave = tid >> 6, lane = tid & 63;
  f32x4 acc[4][4];
  #pragma unroll
  for (int i = 0; i < 4; ++i)
    #pragma unroll
    for (int j = 0; j < 4; ++j) acc[i][j] = (f32x4){0.f, 0.f, 0.f, 0.f};
  const u16* Ab = A + (size_t)tm * KT_TOT * 4096;
  const u16* Bb = B + (size_t)tn * KT_TOT * 4096;
  const int mbase = (wave >> 1) * 4;
  const int nbase = (wave & 1) * 4;
  for (int kt = 0; kt < KT_TOT; ++kt){
    __syncthreads();
    const u16* ga = Ab + kt * 4096;
    const u16* gb = Bb + kt * 4096;
    __builtin_amdgcn_global_load_lds((const __attribute__((address_space(1))) void*)(ga + tid * 8),
                                     (__attribute__((address_space(3))) void*)(lds + tid * 8), 16, 0, 0);
    __builtin_amdgcn_global_load_lds((const __attribute__((address_space(1))) void*)(ga + 2048 + tid * 8),
                                     (__attribute__((address_space(3))) void*)(lds + 2048 + tid * 8), 16, 0, 0);
    __builtin_amdgcn_global_load_lds((const __attribute__((address_space(1))) void*)(gb + tid * 8),
                                     (__attribute__((address_space(3))) void*)(lds + 4096 + tid * 8), 16, 0, 0);
    __builtin_amdgcn_global_load_lds((const __attribute__((address_space(1))) void*)(gb + 6144 + tid * 8 - 4096),
                                     (__attribute__((address_space(3))) void*)(lds + 6144 + tid * 8), 16, 0, 0);
    __syncthreads();
    const bf16x8* A8 = (const bf16x8*)lds;
    const bf16x8* B8 = (const bf16x8*)(lds + 4096);
    bf16x8 av[4], bv[4];
    #pragma unroll
    for (int i = 0; i < 4; ++i) av[i] = A8[(mbase + i) * 64 + lane];
    #pragma unroll
    for (int j = 0; j < 4; ++j) bv[j] = B8[(nbase + j) * 64 + lane];
    #pragma unroll
    for (int i = 0; i < 4; ++i)
      #pragma unroll
      for (int j = 0; j < 4; ++j)
        acc[i][j] = __builtin_amdgcn_mfma_f32_16x16x32_bf16(av[i], bv[j], acc[i][j], 0, 0, 0);
  }
  const int r0 = (lane >> 4) * 4, c0 = lane & 15;   // C/D: col=lane&15, row=(lane>>4)*4+reg
  #pragma unroll
  for (int i = 0; i < 4; ++i){
    int m0 = tm * 128 + mbase * 16 + i * 16 + r0;
    #pragma unroll
    for (int j = 0; j < 4; ++j){
      int n0 = tn * 128 + nbase * 16 + j * 16 + c0;
      #pragma unroll
      for (int r = 0; r < 4; ++r){
        int m = m0 + r;
        if (m < M_ROWS) T[(size_t)m * TROW + n0] = f2bf(acc[i][j][r]);
      }
    }
  }
}

// ---------------- K3: per-title encoder (conv-sum + LN + relu + 2 attentions) ------
__global__ __launch_bounds__(256) void encode_k(
    const int* __restrict__ cand, const int* __restrict__ clk,
    const u16* __restrict__ T,
    const float* __restrict__ b1, const float* __restrict__ b2, const float* __restrict__ b3,
    const float* __restrict__ lng, const float* __restrict__ lnb,
    const float* __restrict__ ql, const float* __restrict__ qw,
    float* __restrict__ rc, float* __restrict__ rh){
  __shared__ float dls[90][150];
  __shared__ float sl[90];
  __shared__ float tl[30];
  __shared__ float pbuf[4][150];
  __shared__ int words[30];
  const int t = blockIdx.x;
  const int tid = threadIdx.x, wave = tid >> 6, lane = tid & 63;
  const int* wp; float* outp;
  if (t < 320){ wp = cand + t * 30;                outp = rc + t * 150; }
  else        { wp = clk + (size_t)(t - 320) * 30; outp = rh + (size_t)(t - 320) * 150; }
  if (tid < 30) words[tid] = wp[tid];
  __syncthreads();
  const float invs = 0.057735026918962576f;  // 1/sqrt(300)
  // phase 1: y -> LN -> relu -> d, plus level-attn logits
  for (int p = wave; p < 90; p += 4){
    int l = p / 3, br = p % 3, dil = br + 1;
    const float* bias = (br == 0) ? b1 : ((br == 1) ? b2 : b3);
    int f0 = lane, f1 = lane + 64, f2 = lane + 128;
    float y0 = 0.f, y1 = 0.f, y2 = 0.f;
    #pragma unroll
    for (int tap = 0; tap < 3; ++tap){
      int ls = l + (tap - 1) * dil;
      if (ls >= 0 && ls < 30){
        const u16* row = T + (size_t)words[ls] * TROW + br * 450 + tap * 150;
        y0 += bf2f(row[f0]);
        y1 += bf2f(row[f1]);
        if (f2 < 150) y2 += bf2f(row[f2]);
      }
    }
    y0 += bias[f0]; y1 += bias[f1];
    float s = y0 + y1, ss = y0 * y0 + y1 * y1;
    if (f2 < 150){ y2 += bias[f2]; s += y2; ss += y2 * y2; }
    #pragma unroll
    for (int o = 32; o > 0; o >>= 1){ s += __shfl_xor(s, o, 64); ss += __shfl_xor(ss, o, 64); }
    float mean = s * (1.f / 150.f);
    float var  = ss * (1.f / 150.f) - mean * mean;
    float rstd = rsqrtf(var + 1e-5f);
    float dot = 0.f;
    float d0 = fmaxf((y0 - mean) * rstd * lng[f0] + lnb[f0], 0.f); dls[p][f0] = d0; dot += ql[f0] * d0;
    float d1 = fmaxf((y1 - mean) * rstd * lng[f1] + lnb[f1], 0.f); dls[p][f1] = d1; dot += ql[f1] * d1;
    if (f2 < 150){
      float d2 = fmaxf((y2 - mean) * rstd * lng[f2] + lnb[f2], 0.f); dls[p][f2] = d2; dot += ql[f2] * d2;
    }
    #pragma unroll
    for (int o = 32; o > 0; o >>= 1) dot += __shfl_xor(dot, o, 64);
    if (lane == 0) sl[p] = dot * invs;
  }
  __syncthreads();
  // phase 2: level softmax (3-way, per word position)
  if (tid < 30){
    float a0 = sl[tid * 3], a1 = sl[tid * 3 + 1], a2 = sl[tid * 3 + 2];
    float mx = fmaxf(a0, fmaxf(a1, a2));
    float e0 = expf(a0 - mx), e1 = expf(a1 - mx), e2 = expf(a2 - mx);
    float inv = 1.f / (e0 + e1 + e2);
    sl[tid * 3] = e0 * inv; sl[tid * 3 + 1] = e1 * inv; sl[tid * 3 + 2] = e2 * inv;
  }
  __syncthreads();
  // phase 3: attn per word (kept in regs), word-attn logits
  float at0[8], at1[8], at2[8]; int myl[8]; int nl = 0;
  for (int l = wave; l < 30; l += 4){
    float w0 = sl[l * 3], w1v = sl[l * 3 + 1], w2v = sl[l * 3 + 2];
    int f0 = lane, f1 = lane + 64, f2 = lane + 128;
    float a0 = w0 * dls[l * 3][f0] + w1v * dls[l * 3 + 1][f0] + w2v * dls[l * 3 + 2][f0];
    float a1 = w0 * dls[l * 3][f1] + w1v * dls[l * 3 + 1][f1] + w2v * dls[l * 3 + 2][f1];
    float a2 = 0.f;
    float dot = qw[f0] * a0 + qw[f1] * a1;
    if (f2 < 150){
      a2 = w0 * dls[l * 3][f2] + w1v * dls[l * 3 + 1][f2] + w2v * dls[l * 3 + 2][f2];
      dot += qw[f2] * a2;
    }
    #pragma unroll
    for (int o = 32; o > 0; o >>= 1) dot += __shfl_xor(dot, o, 64);
    if (lane == 0) tl[l] = dot * invs;
    at0[nl] = a0; at1[nl] = a1; at2[nl] = a2; myl[nl] = l; ++nl;
  }
  __syncthreads();
  // phase 4: word softmax + per-wave partial reprs
  float mx = -1e30f;
  for (int l = 0; l < 30; ++l) mx = fmaxf(mx, tl[l]);
  float den = 0.f;
  for (int l = 0; l < 30; ++l) den += expf(tl[l] - mx);
  float invden = 1.f / den;
  float p0 = 0.f, p1 = 0.f, p2 = 0.f;
  for (int q = 0; q < nl; ++q){
    float wwv = expf(tl[myl[q]] - mx) * invden;
    p0 += wwv * at0[q]; p1 += wwv * at1[q]; p2 += wwv * at2[q];
  }
  pbuf[wave][lane] = p0;
  pbuf[wave][lane + 64] = p1;
  if (lane + 128 < 150) pbuf[wave][lane + 128] = p2;
  __syncthreads();
  if (tid < 150) outp[tid] = pbuf[0][tid] + pbuf[1][tid] + pbuf[2][tid] + pbuf[3][tid];
}

// ---------------- K4: scores -> logits -> log_softmax ----------------
__global__ __launch_bounds__(64) void final_k(const float* __restrict__ rc, const float* __restrict__ rh,
                                              const float* __restrict__ lw, const float* __restrict__ lb,
                                              float* __restrict__ out){
  __shared__ float sc[5][50];
  __shared__ float lg[5];
  const int b = blockIdx.x, tid = threadIdx.x;
  const float* C = rc + b * 5 * 150;
  const float* H = rh + (size_t)b * 50 * 150;
  for (int p = tid; p < 250; p += 64){
    int c = p / 50, h = p % 50;
    float s = 0.f;
    for (int k = 0; k < 150; ++k) s += C[c * 150 + k] * H[h * 150 + k];
    sc[c][h] = s;
  }
  __syncthreads();
  if (tid < 5){
    float s = lb[0];
    for (int h = 0; h < 50; ++h) s += sc[tid][h] * lw[h];
    lg[tid] = s;
  }
  __syncthreads();
  if (tid < 5){
    float mx = fmaxf(fmaxf(fmaxf(lg[0], lg[1]), fmaxf(lg[2], lg[3])), lg[4]);
    float den = 0.f;
    for (int c = 0; c < 5; ++c) den += expf(lg[c] - mx);
    out[b * 5 + tid] = lg[tid] - mx - logf(den);
  }
}

extern "C" void kernel_launch(void* const* d_in, const int* in_sizes, int n_in,
                              void* d_out, int out_size, void* d_ws, size_t ws_size,
                              hipStream_t stream){
  const int*   cand = (const int*)d_in[0];
  const int*   clk  = (const int*)d_in[1];
  const float* emb  = (const float*)d_in[2];
  const float* w1   = (const float*)d_in[3];
  const float* b1   = (const float*)d_in[4];
  const float* w2   = (const float*)d_in[5];
  const float* b2   = (const float*)d_in[6];
  const float* w3   = (const float*)d_in[7];
  const float* b3   = (const float*)d_in[8];
  const float* lng  = (const float*)d_in[9];
  const float* lnb  = (const float*)d_in[10];
  const float* ql   = (const float*)d_in[11];
  const float* qw   = (const float*)d_in[12];
  const float* lw   = (const float*)d_in[13];
  const float* lb   = (const float*)d_in[14];
  float* out = (float*)d_out;

  char* ws = (char*)d_ws;
  const size_t szA = (size_t)M_TILES * KT_TOT * 8192;   // 64,061,440
  const size_t szB = (size_t)N_TILES * KT_TOT * 8192;   //  1,802,240
  const size_t szT = (size_t)M_ROWS * TROW * 2;         // 140,800,000
  u16*   A  = (u16*)ws;
  u16*   B  = (u16*)(ws + szA);
  u16*   T  = (u16*)(ws + szA + szB);
  float* rc = (float*)(ws + szA + szB + szT);
  float* rh = rc + 320 * 150;

  build_A<<<(M_PAD * 80 + 255) / 256, 256, 0, stream>>>(emb, A);
  build_B<<<(N_PAD * 640 + 255) / 256, 256, 0, stream>>>(w1, w2, w3, B);
  gemm_k<<<dim3(M_TILES, N_TILES), 256, 0, stream>>>(A, B, T);
  encode_k<<<3520, 256, 0, stream>>>(cand, clk, T, b1, b2, b3, lng, lnb, ql, qw, rc, rh);
  final_k<<<64, 64, 0, stream>>>(rc, rh, lw, lb, out);
}

// Round 2
// 588.123 us; speedup vs baseline: 1.1674x; 1.1674x over previous
//
#include <hip/hip_runtime.h>

typedef unsigned short u16;
typedef unsigned int   u32;
typedef __bf16 bf16x8 __attribute__((ext_vector_type(8)));
typedef float  f32x4  __attribute__((ext_vector_type(4)));

#define M_ROWS 50000
#define M_PAD  50048
#define M_TILES 391
#define N_REAL 1440     // 3 br * 3 tap * 160 (f padded 150->160)
#define N_PAD  1536
#define N_TILES 12
#define K_DIM  300
#define K_PAD  320
#define KT_HALF 10
#define KT_TOT  20      // hi/lo split: K = 640
#define TROW   1440     // u16 elements per T row (2880 B, 16B-aligned)

static __device__ __forceinline__ u16 f2bf(float x){
  union { float f; u32 u; } a; a.f = x;
  u32 r = a.u + 0x7fffu + ((a.u >> 16) & 1u);   // RNE
  return (u16)(r >> 16);
}
static __device__ __forceinline__ float bf2f(u16 h){
  union { u32 u; float f; } a; a.u = ((u32)h) << 16; return a.f;
}
static __device__ __forceinline__ float hi2f(u32 w){
  union { u32 u; float f; } a; a.u = w & 0xffff0000u; return a.f;
}
static __device__ __forceinline__ float lo2f(u32 w){
  union { u32 u; float f; } a; a.u = w << 16; return a.f;
}

// ---------------- K1a: embedding -> swizzled bf16 hi/lo A ----------------
__global__ void build_A(const float* __restrict__ emb, u16* __restrict__ A){
  int t = blockIdx.x * 256 + threadIdx.x;
  if (t >= M_PAD * 80) return;
  int m = t / 80, kg_all = t % 80;
  int half = (kg_all >= 40) ? 1 : 0;
  int kgh = kg_all - half * 40;               // 0..39 within half
  int k0 = kgh * 8;
  int kt = half * KT_HALF + (kgh >> 2);
  int kgl = kgh & 3;
  int tile = m >> 7, ml = m & 127, mb = ml >> 4, row = ml & 15;
  size_t off = ((size_t)tile * KT_TOT + kt) * 4096 + mb * 512 + kgl * 128 + row * 8;
  union { uint4 q; u16 s[8]; } p;
  #pragma unroll
  for (int j = 0; j < 8; ++j){
    int k = k0 + j;
    float x = 0.f;
    if (m < M_ROWS && k < K_DIM){
      float e = emb[(size_t)m * K_DIM + k];
      u16 hi = f2bf(e);
      x = half ? (e - bf2f(hi)) : bf2f(hi);
    }
    p.s[j] = f2bf(x);
  }
  *(uint4*)(A + off) = p.q;
}

// ---------------- K1b: w1/w2/w3 -> swizzled bf16 B (padded f, dup hi/lo K) -------
// Logical B^T[n][k]: n = br*480 + tap*160 + f (f<150 real), value = w_br[tap][k][f].
__global__ void build_B(const float* __restrict__ w1, const float* __restrict__ w2,
                        const float* __restrict__ w3, u16* __restrict__ B){
  int t = blockIdx.x * 256 + threadIdx.x;
  if (t >= N_PAD * 640) return;
  int n = t / 640, k = t % 640;
  int kk = k % K_PAD;
  float x = 0.f;
  if (n < N_REAL && kk < K_DIM){
    int br = n / 480, rem = n % 480, tap = rem / 160, f = rem % 160;
    if (f < 150){
      const float* w = (br == 0) ? w1 : ((br == 1) ? w2 : w3);
      x = w[(tap * K_DIM + kk) * 150 + f];
    }
  }
  int tn = n >> 7, nl = n & 127, nb = nl >> 4, col = nl & 15;
  int kt = k >> 5, kl = k & 31, kg = kl >> 3, k8 = kl & 7;
  B[((size_t)tn * KT_TOT + kt) * 4096 + nb * 512 + kg * 128 + col * 8 + k8] = f2bf(x);
}

// ---------------- K2: T = A x B^T  (m97-style 128x128 tile, BK=32) ----------------
__global__ __launch_bounds__(256) void gemm_k(const u16* __restrict__ A, const u16* __restrict__ B,
                                              u16* __restrict__ T){
  __shared__ __align__(16) u16 lds[8192];   // A tile 8KB | B tile 8KB
  const int tm = blockIdx.x, tn = blockIdx.y;
  const int tid = threadIdx.x, wave = tid >> 6, lane = tid & 63;
  f32x4 acc[4][4];
  #pragma unroll
  for (int i = 0; i < 4; ++i)
    #pragma unroll
    for (int j = 0; j < 4; ++j) acc[i][j] = (f32x4){0.f, 0.f, 0.f, 0.f};
  const u16* Ab = A + (size_t)tm * KT_TOT * 4096;
  const u16* Bb = B + (size_t)tn * KT_TOT * 4096;
  const int mbase = (wave >> 1) * 4;
  const int nbase = (wave & 1) * 4;
  for (int kt = 0; kt < KT_TOT; ++kt){
    __syncthreads();
    const u16* ga = Ab + kt * 4096;
    const u16* gb = Bb + kt * 4096;
    __builtin_amdgcn_global_load_lds((const __attribute__((address_space(1))) void*)(ga + tid * 8),
                                     (__attribute__((address_space(3))) void*)(lds + tid * 8), 16, 0, 0);
    __builtin_amdgcn_global_load_lds((const __attribute__((address_space(1))) void*)(ga + 2048 + tid * 8),
                                     (__attribute__((address_space(3))) void*)(lds + 2048 + tid * 8), 16, 0, 0);
    __builtin_amdgcn_global_load_lds((const __attribute__((address_space(1))) void*)(gb + tid * 8),
                                     (__attribute__((address_space(3))) void*)(lds + 4096 + tid * 8), 16, 0, 0);
    __builtin_amdgcn_global_load_lds((const __attribute__((address_space(1))) void*)(gb + 2048 + tid * 8),
                                     (__attribute__((address_space(3))) void*)(lds + 6144 + tid * 8), 16, 0, 0);
    __syncthreads();
    const bf16x8* A8 = (const bf16x8*)lds;
    const bf16x8* B8 = (const bf16x8*)(lds + 4096);
    bf16x8 av[4], bv[4];
    #pragma unroll
    for (int i = 0; i < 4; ++i) av[i] = A8[(mbase + i) * 64 + lane];
    #pragma unroll
    for (int j = 0; j < 4; ++j) bv[j] = B8[(nbase + j) * 64 + lane];
    #pragma unroll
    for (int i = 0; i < 4; ++i)
      #pragma unroll
      for (int j = 0; j < 4; ++j)
        acc[i][j] = __builtin_amdgcn_mfma_f32_16x16x32_bf16(av[i], bv[j], acc[i][j], 0, 0, 0);
  }
  const int r0 = (lane >> 4) * 4, c0 = lane & 15;   // C/D: col=lane&15, row=(lane>>4)*4+reg
  #pragma unroll
  for (int i = 0; i < 4; ++i){
    int m0 = tm * 128 + mbase * 16 + i * 16 + r0;
    #pragma unroll
    for (int j = 0; j < 4; ++j){
      int n0 = tn * 128 + nbase * 16 + j * 16 + c0;
      if (n0 < N_REAL){
        #pragma unroll
        for (int r = 0; r < 4; ++r){
          int m = m0 + r;
          if (m < M_ROWS) T[(size_t)m * TROW + n0] = f2bf(acc[i][j][r]);
        }
      }
    }
  }
}

// ---------------- K3: per-title encoder -------------------------------------------
// Phase 0: cooperative vectorized gather of T rows -> y sums in LDS.
// Phase 1: LN + relu + level-attn logits (d overwrites y in place).
// Phase 2-4: level softmax, word attn, output.
__global__ __launch_bounds__(256) void encode_k(
    const int* __restrict__ cand, const int* __restrict__ clk,
    const u16* __restrict__ T,
    const float* __restrict__ b1, const float* __restrict__ b2, const float* __restrict__ b3,
    const float* __restrict__ lng, const float* __restrict__ lnb,
    const float* __restrict__ ql, const float* __restrict__ qw,
    float* __restrict__ rc, float* __restrict__ rh){
  __shared__ float ybuf[90][160];   // y, then d in place (57.6 KB)
  __shared__ float sl[90];
  __shared__ float tl[30];
  __shared__ float pbuf[4][150];
  __shared__ int words[30];
  const int t = blockIdx.x;
  const int tid = threadIdx.x, wave = tid >> 6, lane = tid & 63;
  const int* wp; float* outp;
  if (t < 320){ wp = cand + t * 30;                outp = rc + t * 150; }
  else        { wp = clk + (size_t)(t - 320) * 30; outp = rh + (size_t)(t - 320) * 150; }
  if (tid < 30) words[tid] = wp[tid];
  __syncthreads();
  const float invs = 0.057735026918962576f;  // 1/sqrt(300)

  // ---- phase 0: gather. items = p(90) x fg(19); each: 3 taps x dwordx4 load ----
  #pragma unroll
  for (int it = 0; it < 7; ++it){
    int item = tid + it * 256;
    if (item < 1710){
      int p = item / 19, fg = item - p * 19;    // p = l*3+br
      int l = p / 3, br = p - l * 3, dil = br + 1;
      float a0 = 0.f, a1 = 0.f, a2 = 0.f, a3 = 0.f, a4 = 0.f, a5 = 0.f, a6 = 0.f, a7 = 0.f;
      #pragma unroll
      for (int tap = 0; tap < 3; ++tap){
        int ls = l + (tap - 1) * dil;
        if (ls >= 0 && ls < 30){
          const uint4* src = (const uint4*)(T + (size_t)words[ls] * TROW + br * 480 + tap * 160 + fg * 8);
          uint4 v = *src;
          a0 += lo2f(v.x); a1 += hi2f(v.x);
          a2 += lo2f(v.y); a3 += hi2f(v.y);
          a4 += lo2f(v.z); a5 += hi2f(v.z);
          a6 += lo2f(v.w); a7 += hi2f(v.w);
        }
      }
      float4* dst = (float4*)&ybuf[p][fg * 8];
      dst[0] = (float4){a0, a1, a2, a3};
      dst[1] = (float4){a4, a5, a6, a7};
    }
  }
  __syncthreads();

  // ---- phase 1: LN + relu + level-attn logit; d overwrites y in place ----
  for (int p = wave; p < 90; p += 4){
    int br = p % 3;
    const float* bias = (br == 0) ? b1 : ((br == 1) ? b2 : b3);
    int f0 = lane, f1 = lane + 64, f2 = lane + 128;
    float y0 = ybuf[p][f0] + bias[f0];
    float y1 = ybuf[p][f1] + bias[f1];
    float y2 = 0.f;
    float s = y0 + y1, ss = y0 * y0 + y1 * y1;
    if (f2 < 150){ y2 = ybuf[p][f2] + bias[f2]; s += y2; ss += y2 * y2; }
    #pragma unroll
    for (int o = 32; o > 0; o >>= 1){ s += __shfl_xor(s, o, 64); ss += __shfl_xor(ss, o, 64); }
    float mean = s * (1.f / 150.f);
    float var  = ss * (1.f / 150.f) - mean * mean;
    float rstd = rsqrtf(var + 1e-5f);
    float dot = 0.f;
    float d0 = fmaxf((y0 - mean) * rstd * lng[f0] + lnb[f0], 0.f); ybuf[p][f0] = d0; dot += ql[f0] * d0;
    float d1 = fmaxf((y1 - mean) * rstd * lng[f1] + lnb[f1], 0.f); ybuf[p][f1] = d1; dot += ql[f1] * d1;
    if (f2 < 150){
      float d2 = fmaxf((y2 - mean) * rstd * lng[f2] + lnb[f2], 0.f); ybuf[p][f2] = d2; dot += ql[f2] * d2;
    }
    #pragma unroll
    for (int o = 32; o > 0; o >>= 1) dot += __shfl_xor(dot, o, 64);
    if (lane == 0) sl[p] = dot * invs;
  }
  __syncthreads();

  // ---- phase 2: level softmax (3-way, per word position) ----
  if (tid < 30){
    float a0 = sl[tid * 3], a1 = sl[tid * 3 + 1], a2 = sl[tid * 3 + 2];
    float mx = fmaxf(a0, fmaxf(a1, a2));
    float e0 = expf(a0 - mx), e1 = expf(a1 - mx), e2 = expf(a2 - mx);
    float inv = 1.f / (e0 + e1 + e2);
    sl[tid * 3] = e0 * inv; sl[tid * 3 + 1] = e1 * inv; sl[tid * 3 + 2] = e2 * inv;
  }
  __syncthreads();

  // ---- phase 3: attn per word (regs) + word-attn logits ----
  float at0[8], at1[8], at2[8]; int myl[8]; int nl = 0;
  for (int l = wave; l < 30; l += 4){
    float w0 = sl[l * 3], w1v = sl[l * 3 + 1], w2v = sl[l * 3 + 2];
    int f0 = lane, f1 = lane + 64, f2 = lane + 128;
    float a0 = w0 * ybuf[l * 3][f0] + w1v * ybuf[l * 3 + 1][f0] + w2v * ybuf[l * 3 + 2][f0];
    float a1 = w0 * ybuf[l * 3][f1] + w1v * ybuf[l * 3 + 1][f1] + w2v * ybuf[l * 3 + 2][f1];
    float a2 = 0.f;
    float dot = qw[f0] * a0 + qw[f1] * a1;
    if (f2 < 150){
      a2 = w0 * ybuf[l * 3][f2] + w1v * ybuf[l * 3 + 1][f2] + w2v * ybuf[l * 3 + 2][f2];
      dot += qw[f2] * a2;
    }
    #pragma unroll
    for (int o = 32; o > 0; o >>= 1) dot += __shfl_xor(dot, o, 64);
    if (lane == 0) tl[l] = dot * invs;
    at0[nl] = a0; at1[nl] = a1; at2[nl] = a2; myl[nl] = l; ++nl;
  }
  __syncthreads();

  // ---- phase 4: word softmax + per-wave partial reprs ----
  float mx = -1e30f;
  for (int l = 0; l < 30; ++l) mx = fmaxf(mx, tl[l]);
  float den = 0.f;
  for (int l = 0; l < 30; ++l) den += expf(tl[l] - mx);
  float invden = 1.f / den;
  float p0 = 0.f, p1 = 0.f, p2 = 0.f;
  for (int q = 0; q < nl; ++q){
    float wwv = expf(tl[myl[q]] - mx) * invden;
    p0 += wwv * at0[q]; p1 += wwv * at1[q]; p2 += wwv * at2[q];
  }
  pbuf[wave][lane] = p0;
  pbuf[wave][lane + 64] = p1;
  if (lane + 128 < 150) pbuf[wave][lane + 128] = p2;
  __syncthreads();
  if (tid < 150) outp[tid] = pbuf[0][tid] + pbuf[1][tid] + pbuf[2][tid] + pbuf[3][tid];
}

// ---------------- K4: scores -> logits -> log_softmax ----------------
__global__ __launch_bounds__(64) void final_k(const float* __restrict__ rc, const float* __restrict__ rh,
                                              const float* __restrict__ lw, const float* __restrict__ lb,
                                              float* __restrict__ out){
  __shared__ float sc[5][50];
  __shared__ float lg[5];
  const int b = blockIdx.x, tid = threadIdx.x;
  const float* C = rc + b * 5 * 150;
  const float* H = rh + (size_t)b * 50 * 150;
  for (int p = tid; p < 250; p += 64){
    int c = p / 50, h = p % 50;
    float s = 0.f;
    for (int k = 0; k < 150; ++k) s += C[c * 150 + k] * H[h * 150 + k];
    sc[c][h] = s;
  }
  __syncthreads();
  if (tid < 5){
    float s = lb[0];
    for (int h = 0; h < 50; ++h) s += sc[tid][h] * lw[h];
    lg[tid] = s;
  }
  __syncthreads();
  if (tid < 5){
    float mx = fmaxf(fmaxf(fmaxf(lg[0], lg[1]), fmaxf(lg[2], lg[3])), lg[4]);
    float den = 0.f;
    for (int c = 0; c < 5; ++c) den += expf(lg[c] - mx);
    out[b * 5 + tid] = lg[tid] - mx - logf(den);
  }
}

extern "C" void kernel_launch(void* const* d_in, const int* in_sizes, int n_in,
                              void* d_out, int out_size, void* d_ws, size_t ws_size,
                              hipStream_t stream){
  const int*   cand = (const int*)d_in[0];
  const int*   clk  = (const int*)d_in[1];
  const float* emb  = (const float*)d_in[2];
  const float* w1   = (const float*)d_in[3];
  const float* b1   = (const float*)d_in[4];
  const float* w2   = (const float*)d_in[5];
  const float* b2   = (const float*)d_in[6];
  const float* w3   = (const float*)d_in[7];
  const float* b3   = (const float*)d_in[8];
  const float* lng  = (const float*)d_in[9];
  const float* lnb  = (const float*)d_in[10];
  const float* ql   = (const float*)d_in[11];
  const float* qw   = (const float*)d_in[12];
  const float* lw   = (const float*)d_in[13];
  const float* lb   = (const float*)d_in[14];
  float* out = (float*)d_out;

  char* ws = (char*)d_ws;
  const size_t szA = (size_t)M_TILES * KT_TOT * 8192;   // 64,061,440
  const size_t szB = (size_t)N_TILES * KT_TOT * 8192;   //  1,966,080
  const size_t szT = (size_t)M_ROWS * TROW * 2;         // 144,000,000
  u16*   A  = (u16*)ws;
  u16*   B  = (u16*)(ws + szA);
  u16*   T  = (u16*)(ws + szA + szB);
  float* rc = (float*)(ws + szA + szB + szT);
  float* rh = rc + 320 * 150;

  build_A<<<(M_PAD * 80 + 255) / 256, 256, 0, stream>>>(emb, A);
  build_B<<<(N_PAD * 640 + 255) / 256, 256, 0, stream>>>(w1, w2, w3, B);
  gemm_k<<<dim3(M_TILES, N_TILES), 256, 0, stream>>>(A, B, T);
  encode_k<<<3520, 256, 0, stream>>>(cand, clk, T, b1, b2, b3, lng, lnb, ql, qw, rc, rh);
  final_k<<<64, 64, 0, stream>>>(rc, rh, lw, lb, out);
}

// Round 3
// 404.318 us; speedup vs baseline: 1.6980x; 1.4546x over previous
//
#include <hip/hip_runtime.h>

typedef unsigned short u16;
typedef unsigned int   u32;
typedef __bf16 bf16x8 __attribute__((ext_vector_type(8)));
typedef float  f32x4  __attribute__((ext_vector_type(4)));

#define M_ROWS 50000
#define M_PAD  50048
#define M_TILES 391
#define N_REAL 1440     // 3 br * 3 tap * 160 (f padded 150->160)
#define N_PAD  1536
#define N_TILES 12
#define K_DIM  300
#define K_PAD  320
#define KT     10       // 320 / 32, plain bf16 (no hi/lo split)
#define TROW   1440     // u16 elements per T row (2880 B, 16B-aligned)

static __device__ __forceinline__ u16 f2bf(float x){
  union { float f; u32 u; } a; a.f = x;
  u32 r = a.u + 0x7fffu + ((a.u >> 16) & 1u);   // RNE
  return (u16)(r >> 16);
}
static __device__ __forceinline__ float bf2f(u16 h){
  union { u32 u; float f; } a; a.u = ((u32)h) << 16; return a.f;
}
static __device__ __forceinline__ float hi2f(u32 w){
  union { u32 u; float f; } a; a.u = w & 0xffff0000u; return a.f;
}
static __device__ __forceinline__ float lo2f(u32 w){
  union { u32 u; float f; } a; a.u = w << 16; return a.f;
}

// ---------------- K1a: embedding -> swizzled bf16 A ----------------
// A layout: [tile_m(391)][kt(10)][8192B]; within tile, (m_local,k_local):
//   off_u16 = mb*512 + kg*128 + row*8 + k8  -> lane*16B chunk == one MFMA A-fragment.
__global__ void build_A(const float* __restrict__ emb, u16* __restrict__ A){
  int t = blockIdx.x * 256 + threadIdx.x;
  if (t >= M_PAD * 40) return;
  int m = t / 40, kg = t % 40;
  int k0 = kg * 8;
  int kt = kg >> 2, kgl = kg & 3;
  int tile = m >> 7, ml = m & 127, mb = ml >> 4, row = ml & 15;
  size_t off = ((size_t)tile * KT + kt) * 4096 + mb * 512 + kgl * 128 + row * 8;
  union { uint4 q; u16 s[8]; } p;
  #pragma unroll
  for (int j = 0; j < 8; ++j){
    int k = k0 + j;
    float x = 0.f;
    if (m < M_ROWS && k < K_DIM) x = emb[(size_t)m * K_DIM + k];
    p.s[j] = f2bf(x);
  }
  *(uint4*)(A + off) = p.q;
}

// ---------------- K1b: w1/w2/w3 -> swizzled bf16 B (padded f) --------------------
// Logical B^T[n][k]: n = br*480 + tap*160 + f (f<150 real), value = w_br[tap][k][f].
__global__ void build_B(const float* __restrict__ w1, const float* __restrict__ w2,
                        const float* __restrict__ w3, u16* __restrict__ B){
  int t = blockIdx.x * 256 + threadIdx.x;
  if (t >= N_PAD * K_PAD) return;
  int n = t / K_PAD, k = t % K_PAD;
  float x = 0.f;
  if (n < N_REAL && k < K_DIM){
    int br = n / 480, rem = n % 480, tap = rem / 160, f = rem % 160;
    if (f < 150){
      const float* w = (br == 0) ? w1 : ((br == 1) ? w2 : w3);
      x = w[(tap * K_DIM + k) * 150 + f];
    }
  }
  int tn = n >> 7, nl = n & 127, nb = nl >> 4, col = nl & 15;
  int kt = k >> 5, kl = k & 31, kg = kl >> 3, k8 = kl & 7;
  B[((size_t)tn * KT + kt) * 4096 + nb * 512 + kg * 128 + col * 8 + k8] = f2bf(x);
}

// ---------------- K2: T = A x B^T  (m97-style 128x128 tile, BK=32) ----------------
__global__ __launch_bounds__(256) void gemm_k(const u16* __restrict__ A, const u16* __restrict__ B,
                                              u16* __restrict__ T){
  __shared__ __align__(16) u16 lds[8192];   // A tile 8KB | B tile 8KB
  const int tm = blockIdx.x, tn = blockIdx.y;
  const int tid = threadIdx.x, wave = tid >> 6, lane = tid & 63;
  f32x4 acc[4][4];
  #pragma unroll
  for (int i = 0; i < 4; ++i)
    #pragma unroll
    for (int j = 0; j < 4; ++j) acc[i][j] = (f32x4){0.f, 0.f, 0.f, 0.f};
  const u16* Ab = A + (size_t)tm * KT * 4096;
  const u16* Bb = B + (size_t)tn * KT * 4096;
  const int mbase = (wave >> 1) * 4;
  const int nbase = (wave & 1) * 4;
  for (int kt = 0; kt < KT; ++kt){
    __syncthreads();
    const u16* ga = Ab + kt * 4096;
    const u16* gb = Bb + kt * 4096;
    __builtin_amdgcn_global_load_lds((const __attribute__((address_space(1))) void*)(ga + tid * 8),
                                     (__attribute__((address_space(3))) void*)(lds + tid * 8), 16, 0, 0);
    __builtin_amdgcn_global_load_lds((const __attribute__((address_space(1))) void*)(ga + 2048 + tid * 8),
                                     (__attribute__((address_space(3))) void*)(lds + 2048 + tid * 8), 16, 0, 0);
    __builtin_amdgcn_global_load_lds((const __attribute__((address_space(1))) void*)(gb + tid * 8),
                                     (__attribute__((address_space(3))) void*)(lds + 4096 + tid * 8), 16, 0, 0);
    __builtin_amdgcn_global_load_lds((const __attribute__((address_space(1))) void*)(gb + 2048 + tid * 8),
                                     (__attribute__((address_space(3))) void*)(lds + 6144 + tid * 8), 16, 0, 0);
    __syncthreads();
    const bf16x8* A8 = (const bf16x8*)lds;
    const bf16x8* B8 = (const bf16x8*)(lds + 4096);
    bf16x8 av[4], bv[4];
    #pragma unroll
    for (int i = 0; i < 4; ++i) av[i] = A8[(mbase + i) * 64 + lane];
    #pragma unroll
    for (int j = 0; j < 4; ++j) bv[j] = B8[(nbase + j) * 64 + lane];
    #pragma unroll
    for (int i = 0; i < 4; ++i)
      #pragma unroll
      for (int j = 0; j < 4; ++j)
        acc[i][j] = __builtin_amdgcn_mfma_f32_16x16x32_bf16(av[i], bv[j], acc[i][j], 0, 0, 0);
  }
  const int r0 = (lane >> 4) * 4, c0 = lane & 15;   // C/D: col=lane&15, row=(lane>>4)*4+reg
  #pragma unroll
  for (int i = 0; i < 4; ++i){
    int m0 = tm * 128 + mbase * 16 + i * 16 + r0;
    #pragma unroll
    for (int j = 0; j < 4; ++j){
      int n0 = tn * 128 + nbase * 16 + j * 16 + c0;
      if (n0 < N_REAL){
        #pragma unroll
        for (int r = 0; r < 4; ++r){
          int m = m0 + r;
          if (m < M_ROWS) T[(size_t)m * TROW + n0] = f2bf(acc[i][j][r]);
        }
      }
    }
  }
}

// ---------------- K3: per-title encoder -------------------------------------------
// Phase 0: cooperative vectorized gather of T rows -> bf16 y sums in LDS.
// Phase 1: LN + relu + level-attn logits (bf16 d overwrites y in place).
// Phase 2-4: level softmax, word attn, output.
__global__ __launch_bounds__(256, 4) void encode_k(
    const int* __restrict__ cand, const int* __restrict__ clk,
    const u16* __restrict__ T,
    const float* __restrict__ b1, const float* __restrict__ b2, const float* __restrict__ b3,
    const float* __restrict__ lng, const float* __restrict__ lnb,
    const float* __restrict__ ql, const float* __restrict__ qw,
    float* __restrict__ rc, float* __restrict__ rh){
  __shared__ __align__(16) u16 ybuf[90][160];   // y then d, bf16 (28.8 KB)
  __shared__ float sl[90];
  __shared__ float tl[30];
  __shared__ float pbuf[4][152];
  __shared__ int words[30];
  const int t = blockIdx.x;
  const int tid = threadIdx.x, wave = tid >> 6, lane = tid & 63;
  const int* wp; float* outp;
  if (t < 320){ wp = cand + t * 30;                outp = rc + t * 150; }
  else        { wp = clk + (size_t)(t - 320) * 30; outp = rh + (size_t)(t - 320) * 150; }
  if (tid < 30) words[tid] = wp[tid];
  __syncthreads();
  const float invs = 0.057735026918962576f;  // 1/sqrt(300)

  // ---- phase 0: gather. items = p(90) x fg(19); each: 3 taps x dwordx4 load ----
  #pragma unroll
  for (int it = 0; it < 7; ++it){
    int item = tid + it * 256;
    if (item < 1710){
      int p = item / 19, fg = item - p * 19;    // p = l*3+br
      int l = p / 3, br = p - l * 3, dil = br + 1;
      float a0 = 0.f, a1 = 0.f, a2 = 0.f, a3 = 0.f, a4 = 0.f, a5 = 0.f, a6 = 0.f, a7 = 0.f;
      #pragma unroll
      for (int tap = 0; tap < 3; ++tap){
        int ls = l + (tap - 1) * dil;
        if (ls >= 0 && ls < 30){
          uint4 v = *(const uint4*)(T + (size_t)words[ls] * TROW + br * 480 + tap * 160 + fg * 8);
          a0 += lo2f(v.x); a1 += hi2f(v.x);
          a2 += lo2f(v.y); a3 += hi2f(v.y);
          a4 += lo2f(v.z); a5 += hi2f(v.z);
          a6 += lo2f(v.w); a7 += hi2f(v.w);
        }
      }
      union { uint4 q; u16 s[8]; } o;
      o.s[0] = f2bf(a0); o.s[1] = f2bf(a1); o.s[2] = f2bf(a2); o.s[3] = f2bf(a3);
      o.s[4] = f2bf(a4); o.s[5] = f2bf(a5); o.s[6] = f2bf(a6); o.s[7] = f2bf(a7);
      *(uint4*)&ybuf[p][fg * 8] = o.q;        // contiguous 16B/lane -> conflict-free
    }
  }
  __syncthreads();

  // ---- phase 1: LN + relu + level-attn logit; d overwrites y in place ----
  for (int p = wave; p < 90; p += 4){
    int br = p % 3;
    const float* bias = (br == 0) ? b1 : ((br == 1) ? b2 : b3);
    int f0 = lane, f1 = lane + 64, f2 = lane + 128;
    float y0 = bf2f(ybuf[p][f0]) + bias[f0];
    float y1 = bf2f(ybuf[p][f1]) + bias[f1];
    float y2 = 0.f;
    float s = y0 + y1, ss = y0 * y0 + y1 * y1;
    if (f2 < 150){ y2 = bf2f(ybuf[p][f2]) + bias[f2]; s += y2; ss += y2 * y2; }
    #pragma unroll
    for (int o = 32; o > 0; o >>= 1){ s += __shfl_xor(s, o, 64); ss += __shfl_xor(ss, o, 64); }
    float mean = s * (1.f / 150.f);
    float var  = ss * (1.f / 150.f) - mean * mean;
    float rstd = rsqrtf(var + 1e-5f);
    float dot = 0.f;
    float d0 = fmaxf((y0 - mean) * rstd * lng[f0] + lnb[f0], 0.f); ybuf[p][f0] = f2bf(d0); dot += ql[f0] * d0;
    float d1 = fmaxf((y1 - mean) * rstd * lng[f1] + lnb[f1], 0.f); ybuf[p][f1] = f2bf(d1); dot += ql[f1] * d1;
    if (f2 < 150){
      float d2 = fmaxf((y2 - mean) * rstd * lng[f2] + lnb[f2], 0.f); ybuf[p][f2] = f2bf(d2); dot += ql[f2] * d2;
    }
    #pragma unroll
    for (int o = 32; o > 0; o >>= 1) dot += __shfl_xor(dot, o, 64);
    if (lane == 0) sl[p] = dot * invs;
  }
  __syncthreads();

  // ---- phase 2: level softmax (3-way, per word position) ----
  if (tid < 30){
    float a0 = sl[tid * 3], a1 = sl[tid * 3 + 1], a2 = sl[tid * 3 + 2];
    float mx = fmaxf(a0, fmaxf(a1, a2));
    float e0 = expf(a0 - mx), e1 = expf(a1 - mx), e2 = expf(a2 - mx);
    float inv = 1.f / (e0 + e1 + e2);
    sl[tid * 3] = e0 * inv; sl[tid * 3 + 1] = e1 * inv; sl[tid * 3 + 2] = e2 * inv;
  }
  __syncthreads();

  // ---- phase 3: attn per word (regs) + word-attn logits ----
  float at0[8], at1[8], at2[8]; int myl[8]; int nl = 0;
  for (int l = wave; l < 30; l += 4){
    float w0 = sl[l * 3], w1v = sl[l * 3 + 1], w2v = sl[l * 3 + 2];
    int f0 = lane, f1 = lane + 64, f2 = lane + 128;
    float a0 = w0 * bf2f(ybuf[l * 3][f0]) + w1v * bf2f(ybuf[l * 3 + 1][f0]) + w2v * bf2f(ybuf[l * 3 + 2][f0]);
    float a1 = w0 * bf2f(ybuf[l * 3][f1]) + w1v * bf2f(ybuf[l * 3 + 1][f1]) + w2v * bf2f(ybuf[l * 3 + 2][f1]);
    float a2 = 0.f;
    float dot = qw[f0] * a0 + qw[f1] * a1;
    if (f2 < 150){
      a2 = w0 * bf2f(ybuf[l * 3][f2]) + w1v * bf2f(ybuf[l * 3 + 1][f2]) + w2v * bf2f(ybuf[l * 3 + 2][f2]);
      dot += qw[f2] * a2;
    }
    #pragma unroll
    for (int o = 32; o > 0; o >>= 1) dot += __shfl_xor(dot, o, 64);
    if (lane == 0) tl[l] = dot * invs;
    at0[nl] = a0; at1[nl] = a1; at2[nl] = a2; myl[nl] = l; ++nl;
  }
  __syncthreads();

  // ---- phase 4: word softmax + per-wave partial reprs ----
  float mx = -1e30f;
  for (int l = 0; l < 30; ++l) mx = fmaxf(mx, tl[l]);
  float den = 0.f;
  for (int l = 0; l < 30; ++l) den += expf(tl[l] - mx);
  float invden = 1.f / den;
  float p0 = 0.f, p1 = 0.f, p2 = 0.f;
  for (int q = 0; q < nl; ++q){
    float wwv = expf(tl[myl[q]] - mx) * invden;
    p0 += wwv * at0[q]; p1 += wwv * at1[q]; p2 += wwv * at2[q];
  }
  pbuf[wave][lane] = p0;
  pbuf[wave][lane + 64] = p1;
  if (lane + 128 < 150) pbuf[wave][lane + 128] = p2;
  __syncthreads();
  if (tid < 150) outp[tid] = pbuf[0][tid] + pbuf[1][tid] + pbuf[2][tid] + pbuf[3][tid];
}

// ---------------- K4: scores -> logits -> log_softmax ----------------
__global__ __launch_bounds__(64) void final_k(const float* __restrict__ rc, const float* __restrict__ rh,
                                              const float* __restrict__ lw, const float* __restrict__ lb,
                                              float* __restrict__ out){
  __shared__ float sc[5][50];
  __shared__ float lg[5];
  const int b = blockIdx.x, tid = threadIdx.x;
  const float* C = rc + b * 5 * 150;
  const float* H = rh + (size_t)b * 50 * 150;
  for (int p = tid; p < 250; p += 64){
    int c = p / 50, h = p % 50;
    float s = 0.f;
    for (int k = 0; k < 150; ++k) s += C[c * 150 + k] * H[h * 150 + k];
    sc[c][h] = s;
  }
  __syncthreads();
  if (tid < 5){
    float s = lb[0];
    for (int h = 0; h < 50; ++h) s += sc[tid][h] * lw[h];
    lg[tid] = s;
  }
  __syncthreads();
  if (tid < 5){
    float mx = fmaxf(fmaxf(fmaxf(lg[0], lg[1]), fmaxf(lg[2], lg[3])), lg[4]);
    float den = 0.f;
    for (int c = 0; c < 5; ++c) den += expf(lg[c] - mx);
    out[b * 5 + tid] = lg[tid] - mx - logf(den);
  }
}

extern "C" void kernel_launch(void* const* d_in, const int* in_sizes, int n_in,
                              void* d_out, int out_size, void* d_ws, size_t ws_size,
                              hipStream_t stream){
  const int*   cand = (const int*)d_in[0];
  const int*   clk  = (const int*)d_in[1];
  const float* emb  = (const float*)d_in[2];
  const float* w1   = (const float*)d_in[3];
  const float* b1   = (const float*)d_in[4];
  const float* w2   = (const float*)d_in[5];
  const float* b2   = (const float*)d_in[6];
  const float* w3   = (const float*)d_in[7];
  const float* b3   = (const float*)d_in[8];
  const float* lng  = (const float*)d_in[9];
  const float* lnb  = (const float*)d_in[10];
  const float* ql   = (const float*)d_in[11];
  const float* qw   = (const float*)d_in[12];
  const float* lw   = (const float*)d_in[13];
  const float* lb   = (const float*)d_in[14];
  float* out = (float*)d_out;

  char* ws = (char*)d_ws;
  const size_t szA = (size_t)M_TILES * KT * 8192;   // 32,030,720
  const size_t szB = (size_t)N_TILES * KT * 8192;   //     983,040
  const size_t szT = (size_t)M_ROWS * TROW * 2;     // 144,000,000
  u16*   A  = (u16*)ws;
  u16*   B  = (u16*)(ws + szA);
  u16*   T  = (u16*)(ws + szA + szB);
  float* rc = (float*)(ws + szA + szB + szT);
  float* rh = rc + 320 * 150;

  build_A<<<(M_PAD * 40 + 255) / 256, 256, 0, stream>>>(emb, A);
  build_B<<<(N_PAD * K_PAD + 255) / 256, 256, 0, stream>>>(w1, w2, w3, B);
  gemm_k<<<dim3(M_TILES, N_TILES), 256, 0, stream>>>(A, B, T);
  encode_k<<<3520, 256, 0, stream>>>(cand, clk, T, b1, b2, b3, lng, lnb, ql, qw, rc, rh);
  final_k<<<64, 64, 0, stream>>>(rc, rh, lw, lb, out);
}

// Round 4
// 355.257 us; speedup vs baseline: 1.9325x; 1.1381x over previous
//
#include <hip/hip_runtime.h>

typedef unsigned short u16;
typedef unsigned int   u32;
typedef __bf16 bf16x8 __attribute__((ext_vector_type(8)));
typedef float  f32x4  __attribute__((ext_vector_type(4)));

#define M_ROWS 50000
#define M_PAD  50048
#define M_TILES 391
#define N_REAL 1440     // 3 br * 3 tap * 160 (f padded 150->160)
#define N_PAD  1536
#define N_TILES 12
#define K_DIM  300
#define K_PAD  320
#define KT     10       // 320 / 32, plain bf16
#define TROW   1440     // u16 elements per T row (2880 B, 16B-aligned)
#define YCOL   152      // LDS ybuf row width (19 groups * 8)

static __device__ __forceinline__ u16 f2bf(float x){
  union { float f; u32 u; } a; a.f = x;
  u32 r = a.u + 0x7fffu + ((a.u >> 16) & 1u);   // RNE
  return (u16)(r >> 16);
}
static __device__ __forceinline__ float bf2f(u16 h){
  union { u32 u; float f; } a; a.u = ((u32)h) << 16; return a.f;
}
static __device__ __forceinline__ float hi2f(u32 w){
  union { u32 u; float f; } a; a.u = w & 0xffff0000u; return a.f;
}
static __device__ __forceinline__ float lo2f(u32 w){
  union { u32 u; float f; } a; a.u = w << 16; return a.f;
}

// ---- DPP wave reduction: sum of all 64 lanes lands in lane 63 (6 VALU ops) ----
template<int CTRL>
static __device__ __forceinline__ float dppadd(float x){
  union { float f; int i; } a, b; a.f = x;
  b.i = __builtin_amdgcn_update_dpp(0, a.i, CTRL, 0xf, 0xf, true);
  return x + b.f;
}
static __device__ __forceinline__ float wsum63(float x){
  x = dppadd<0x111>(x);  // row_shr:1
  x = dppadd<0x112>(x);  // row_shr:2
  x = dppadd<0x114>(x);  // row_shr:4
  x = dppadd<0x118>(x);  // row_shr:8
  x = dppadd<0x142>(x);  // row_bcast:15
  x = dppadd<0x143>(x);  // row_bcast:31
  return x;              // lane 63 holds the full sum
}
static __device__ __forceinline__ float rdl63(float x){
  union { float f; int i; } a; a.f = x;
  union { int i; float f; } r; r.i = __builtin_amdgcn_readlane(a.i, 63);
  return r.f;
}

// ---------------- K1a: embedding -> swizzled bf16 A ----------------
__global__ void build_A(const float* __restrict__ emb, u16* __restrict__ A){
  int t = blockIdx.x * 256 + threadIdx.x;
  if (t >= M_PAD * 40) return;
  int m = t / 40, kg = t % 40;
  int k0 = kg * 8;
  int kt = kg >> 2, kgl = kg & 3;
  int tile = m >> 7, ml = m & 127, mb = ml >> 4, row = ml & 15;
  size_t off = ((size_t)tile * KT + kt) * 4096 + mb * 512 + kgl * 128 + row * 8;
  union { uint4 q; u16 s[8]; } p;
  #pragma unroll
  for (int j = 0; j < 8; ++j){
    int k = k0 + j;
    float x = 0.f;
    if (m < M_ROWS && k < K_DIM) x = emb[(size_t)m * K_DIM + k];
    p.s[j] = f2bf(x);
  }
  *(uint4*)(A + off) = p.q;
}

// ---------------- K1b: w1/w2/w3 -> swizzled bf16 B (padded f) --------------------
__global__ void build_B(const float* __restrict__ w1, const float* __restrict__ w2,
                        const float* __restrict__ w3, u16* __restrict__ B){
  int t = blockIdx.x * 256 + threadIdx.x;
  if (t >= N_PAD * K_PAD) return;
  int n = t / K_PAD, k = t % K_PAD;
  float x = 0.f;
  if (n < N_REAL && k < K_DIM){
    int br = n / 480, rem = n % 480, tap = rem / 160, f = rem % 160;
    if (f < 150){
      const float* w = (br == 0) ? w1 : ((br == 1) ? w2 : w3);
      x = w[(tap * K_DIM + k) * 150 + f];
    }
  }
  int tn = n >> 7, nl = n & 127, nb = nl >> 4, col = nl & 15;
  int kt = k >> 5, kl = k & 31, kg = kl >> 3, k8 = kl & 7;
  B[((size_t)tn * KT + kt) * 4096 + nb * 512 + kg * 128 + col * 8 + k8] = f2bf(x);
}

// ---------------- K2: T = A x B^T  (m97-style 128x128 tile, BK=32) ----------------
__global__ __launch_bounds__(256) void gemm_k(const u16* __restrict__ A, const u16* __restrict__ B,
                                              u16* __restrict__ T){
  __shared__ __align__(16) u16 lds[8192];   // A tile 8KB | B tile 8KB
  const int tm = blockIdx.x, tn = blockIdx.y;
  const int tid = threadIdx.x, wave = tid >> 6, lane = tid & 63;
  f32x4 acc[4][4];
  #pragma unroll
  for (int i = 0; i < 4; ++i)
    #pragma unroll
    for (int j = 0; j < 4; ++j) acc[i][j] = (f32x4){0.f, 0.f, 0.f, 0.f};
  const u16* Ab = A + (size_t)tm * KT * 4096;
  const u16* Bb = B + (size_t)tn * KT * 4096;
  const int mbase = (wave >> 1) * 4;
  const int nbase = (wave & 1) * 4;
  for (int kt = 0; kt < KT; ++kt){
    __syncthreads();
    const u16* ga = Ab + kt * 4096;
    const u16* gb = Bb + kt * 4096;
    __builtin_amdgcn_global_load_lds((const __attribute__((address_space(1))) void*)(ga + tid * 8),
                                     (__attribute__((address_space(3))) void*)(lds + tid * 8), 16, 0, 0);
    __builtin_amdgcn_global_load_lds((const __attribute__((address_space(1))) void*)(ga + 2048 + tid * 8),
                                     (__attribute__((address_space(3))) void*)(lds + 2048 + tid * 8), 16, 0, 0);
    __builtin_amdgcn_global_load_lds((const __attribute__((address_space(1))) void*)(gb + tid * 8),
                                     (__attribute__((address_space(3))) void*)(lds + 4096 + tid * 8), 16, 0, 0);
    __builtin_amdgcn_global_load_lds((const __attribute__((address_space(1))) void*)(gb + 2048 + tid * 8),
                                     (__attribute__((address_space(3))) void*)(lds + 6144 + tid * 8), 16, 0, 0);
    __syncthreads();
    const bf16x8* A8 = (const bf16x8*)lds;
    const bf16x8* B8 = (const bf16x8*)(lds + 4096);
    bf16x8 av[4], bv[4];
    #pragma unroll
    for (int i = 0; i < 4; ++i) av[i] = A8[(mbase + i) * 64 + lane];
    #pragma unroll
    for (int j = 0; j < 4; ++j) bv[j] = B8[(nbase + j) * 64 + lane];
    #pragma unroll
    for (int i = 0; i < 4; ++i)
      #pragma unroll
      for (int j = 0; j < 4; ++j)
        acc[i][j] = __builtin_amdgcn_mfma_f32_16x16x32_bf16(av[i], bv[j], acc[i][j], 0, 0, 0);
  }
  const int r0 = (lane >> 4) * 4, c0 = lane & 15;   // C/D: col=lane&15, row=(lane>>4)*4+reg
  #pragma unroll
  for (int i = 0; i < 4; ++i){
    int m0 = tm * 128 + mbase * 16 + i * 16 + r0;
    #pragma unroll
    for (int j = 0; j < 4; ++j){
      int n0 = tn * 128 + nbase * 16 + j * 16 + c0;
      if (n0 < N_REAL){
        #pragma unroll
        for (int r = 0; r < 4; ++r){
          int m = m0 + r;
          if (m < M_ROWS) T[(size_t)m * TROW + n0] = f2bf(acc[i][j][r]);
        }
      }
    }
  }
}

// ---------------- K3: per-title encoder (word-major, DPP reductions) ---------------
// Phase 0: cooperative vectorized gather of T rows -> bf16 y sums in LDS.
// Phase 1: per-word: 3x(LN + relu + level-logit) with d in regs, wave-local level
//          softmax, attn in regs, word-attn logit. DPP reduces (VALU, no LDS pipe).
// Phase 2: word softmax + output.
__global__ __launch_bounds__(256, 5) void encode_k(
    const int* __restrict__ cand, const int* __restrict__ clk,
    const u16* __restrict__ T,
    const float* __restrict__ b1, const float* __restrict__ b2, const float* __restrict__ b3,
    const float* __restrict__ lng, const float* __restrict__ lnb,
    const float* __restrict__ ql, const float* __restrict__ qw,
    float* __restrict__ rc, float* __restrict__ rh){
  __shared__ __align__(16) u16 ybuf[90][YCOL];   // y, bf16, read-only after gather (27.4 KB)
  __shared__ float tl[30];
  __shared__ float pbuf[4][YCOL];
  __shared__ int words[30];
  const int t = blockIdx.x;
  const int tid = threadIdx.x, wave = tid >> 6, lane = tid & 63;
  const int* wp; float* outp;
  if (t < 320){ wp = cand + t * 30;                outp = rc + t * 150; }
  else        { wp = clk + (size_t)(t - 320) * 30; outp = rh + (size_t)(t - 320) * 150; }
  if (tid < 30) words[tid] = wp[tid];
  __syncthreads();
  const float invs = 0.057735026918962576f;  // 1/sqrt(300)
  const int f0 = lane, f1 = lane + 64, f2 = lane + 128;
  const bool has2 = (f2 < 150);

  // ---- phase 0: gather. items = p(90) x fg(19); each: 3 taps x dwordx4 load ----
  #pragma unroll
  for (int it = 0; it < 7; ++it){
    int item = tid + it * 256;
    if (item < 1710){
      int p = item / 19, fg = item - p * 19;    // p = l*3+br
      int l = p / 3, br = p - l * 3, dil = br + 1;
      float a0 = 0.f, a1 = 0.f, a2 = 0.f, a3 = 0.f, a4 = 0.f, a5 = 0.f, a6 = 0.f, a7 = 0.f;
      #pragma unroll
      for (int tap = 0; tap < 3; ++tap){
        int ls = l + (tap - 1) * dil;
        if (ls >= 0 && ls < 30){
          uint4 v = *(const uint4*)(T + (size_t)words[ls] * TROW + br * 480 + tap * 160 + fg * 8);
          a0 += lo2f(v.x); a1 += hi2f(v.x);
          a2 += lo2f(v.y); a3 += hi2f(v.y);
          a4 += lo2f(v.z); a5 += hi2f(v.z);
          a6 += lo2f(v.w); a7 += hi2f(v.w);
        }
      }
      union { uint4 q; u16 s[8]; } o;
      o.s[0] = f2bf(a0); o.s[1] = f2bf(a1); o.s[2] = f2bf(a2); o.s[3] = f2bf(a3);
      o.s[4] = f2bf(a4); o.s[5] = f2bf(a5); o.s[6] = f2bf(a6); o.s[7] = f2bf(a7);
      *(uint4*)&ybuf[p][fg * 8] = o.q;        // contiguous 16B/lane -> conflict-free
    }
  }

  // preload per-lane params (uniform across words)
  float qlv0 = ql[f0], qlv1 = ql[f1], qlv2 = has2 ? ql[f2] : 0.f;
  float qwv0 = qw[f0], qwv1 = qw[f1], qwv2 = has2 ? qw[f2] : 0.f;
  float lg0 = lng[f0], lg1 = lng[f1], lg2 = has2 ? lng[f2] : 0.f;
  float lb0 = lnb[f0], lb1 = lnb[f1], lb2 = has2 ? lnb[f2] : 0.f;
  float bs[3][3];
  {
    const float* bl[3] = {b1, b2, b3};
    #pragma unroll
    for (int br = 0; br < 3; ++br){
      bs[br][0] = bl[br][f0]; bs[br][1] = bl[br][f1]; bs[br][2] = has2 ? bl[br][f2] : 0.f;
    }
  }
  __syncthreads();

  // ---- phase 1: word-major LN + level-attn (d in regs, DPP reduces) ----
  float at0[8], at1[8], at2[8]; int myl[8]; int nw = 0;
  for (int l = wave; l < 30; l += 4){
    float dr[3][3]; float lvl[3];
    #pragma unroll
    for (int br = 0; br < 3; ++br){
      int p = l * 3 + br;
      float y0 = bf2f(ybuf[p][f0]) + bs[br][0];
      float y1 = bf2f(ybuf[p][f1]) + bs[br][1];
      float y2 = has2 ? (bf2f(ybuf[p][f2]) + bs[br][2]) : 0.f;
      float s  = y0 + y1 + y2;
      float ss = y0 * y0 + y1 * y1 + y2 * y2;
      float st = wsum63(s), sst = wsum63(ss);
      float mean = rdl63(st) * (1.f / 150.f);
      float var  = rdl63(sst) * (1.f / 150.f) - mean * mean;
      float rstd = rsqrtf(var + 1e-5f);
      float d0 = fmaxf((y0 - mean) * rstd * lg0 + lb0, 0.f);
      float d1 = fmaxf((y1 - mean) * rstd * lg1 + lb1, 0.f);
      float d2 = has2 ? fmaxf((y2 - mean) * rstd * lg2 + lb2, 0.f) : 0.f;
      dr[br][0] = d0; dr[br][1] = d1; dr[br][2] = d2;
      float dot = qlv0 * d0 + qlv1 * d1 + qlv2 * d2;
      lvl[br] = rdl63(wsum63(dot)) * invs;
    }
    // wave-local level softmax
    float mx = fmaxf(lvl[0], fmaxf(lvl[1], lvl[2]));
    float e0 = expf(lvl[0] - mx), e1 = expf(lvl[1] - mx), e2 = expf(lvl[2] - mx);
    float inv = 1.f / (e0 + e1 + e2);
    float w0 = e0 * inv, w1v = e1 * inv, w2v = e2 * inv;
    float a0 = w0 * dr[0][0] + w1v * dr[1][0] + w2v * dr[2][0];
    float a1 = w0 * dr[0][1] + w1v * dr[1][1] + w2v * dr[2][1];
    float a2 = w0 * dr[0][2] + w1v * dr[1][2] + w2v * dr[2][2];
    float dot = qwv0 * a0 + qwv1 * a1 + qwv2 * a2;
    float tw = wsum63(dot);
    if (lane == 63) tl[l] = tw * invs;
    at0[nw] = a0; at1[nw] = a1; at2[nw] = a2; myl[nw] = l; ++nw;
  }
  __syncthreads();

  // ---- phase 2: word softmax + per-wave partial reprs ----
  float mx = -1e30f;
  for (int l = 0; l < 30; ++l) mx = fmaxf(mx, tl[l]);
  float den = 0.f;
  for (int l = 0; l < 30; ++l) den += expf(tl[l] - mx);
  float invden = 1.f / den;
  float p0 = 0.f, p1 = 0.f, p2 = 0.f;
  for (int q = 0; q < nw; ++q){
    float wwv = expf(tl[myl[q]] - mx) * invden;
    p0 += wwv * at0[q]; p1 += wwv * at1[q]; p2 += wwv * at2[q];
  }
  pbuf[wave][lane] = p0;
  pbuf[wave][lane + 64] = p1;
  if (has2) pbuf[wave][lane + 128] = p2;
  __syncthreads();
  if (tid < 150) outp[tid] = pbuf[0][tid] + pbuf[1][tid] + pbuf[2][tid] + pbuf[3][tid];
}

// ---------------- K4: scores -> logits -> log_softmax ----------------
__global__ __launch_bounds__(64) void final_k(const float* __restrict__ rc, const float* __restrict__ rh,
                                              const float* __restrict__ lw, const float* __restrict__ lb,
                                              float* __restrict__ out){
  __shared__ float sc[5][50];
  __shared__ float lg[5];
  const int b = blockIdx.x, tid = threadIdx.x;
  const float* C = rc + b * 5 * 150;
  const float* H = rh + (size_t)b * 50 * 150;
  for (int p = tid; p < 250; p += 64){
    int c = p / 50, h = p % 50;
    float s = 0.f;
    for (int k = 0; k < 150; ++k) s += C[c * 150 + k] * H[h * 150 + k];
    sc[c][h] = s;
  }
  __syncthreads();
  if (tid < 5){
    float s = lb[0];
    for (int h = 0; h < 50; ++h) s += sc[tid][h] * lw[h];
    lg[tid] = s;
  }
  __syncthreads();
  if (tid < 5){
    float mx = fmaxf(fmaxf(fmaxf(lg[0], lg[1]), fmaxf(lg[2], lg[3])), lg[4]);
    float den = 0.f;
    for (int c = 0; c < 5; ++c) den += expf(lg[c] - mx);
    out[b * 5 + tid] = lg[tid] - mx - logf(den);
  }
}

extern "C" void kernel_launch(void* const* d_in, const int* in_sizes, int n_in,
                              void* d_out, int out_size, void* d_ws, size_t ws_size,
                              hipStream_t stream){
  const int*   cand = (const int*)d_in[0];
  const int*   clk  = (const int*)d_in[1];
  const float* emb  = (const float*)d_in[2];
  const float* w1   = (const float*)d_in[3];
  const float* b1   = (const float*)d_in[4];
  const float* w2   = (const float*)d_in[5];
  const float* b2   = (const float*)d_in[6];
  const float* w3   = (const float*)d_in[7];
  const float* b3   = (const float*)d_in[8];
  const float* lng  = (const float*)d_in[9];
  const float* lnb  = (const float*)d_in[10];
  const float* ql   = (const float*)d_in[11];
  const float* qw   = (const float*)d_in[12];
  const float* lw   = (const float*)d_in[13];
  const float* lb   = (const float*)d_in[14];
  float* out = (float*)d_out;

  char* ws = (char*)d_ws;
  const size_t szA = (size_t)M_TILES * KT * 8192;   // 32,030,720
  const size_t szB = (size_t)N_TILES * KT * 8192;   //     983,040
  const size_t szT = (size_t)M_ROWS * TROW * 2;     // 144,000,000
  u16*   A  = (u16*)ws;
  u16*   B  = (u16*)(ws + szA);
  u16*   T  = (u16*)(ws + szA + szB);
  float* rc = (float*)(ws + szA + szB + szT);
  float* rh = rc + 320 * 150;

  build_A<<<(M_PAD * 40 + 255) / 256, 256, 0, stream>>>(emb, A);
  build_B<<<(N_PAD * K_PAD + 255) / 256, 256, 0, stream>>>(w1, w2, w3, B);
  gemm_k<<<dim3(M_TILES, N_TILES), 256, 0, stream>>>(A, B, T);
  encode_k<<<3520, 256, 0, stream>>>(cand, clk, T, b1, b2, b3, lng, lnb, ql, qw, rc, rh);
  final_k<<<64, 64, 0, stream>>>(rc, rh, lw, lb, out);
}

// Round 5
// 343.596 us; speedup vs baseline: 1.9981x; 1.0339x over previous
//
#include <hip/hip_runtime.h>

typedef unsigned short u16;
typedef unsigned int   u32;
typedef __bf16 bf16x8 __attribute__((ext_vector_type(8)));
typedef float  f32x4  __attribute__((ext_vector_type(4)));
typedef _Float16 h2 __attribute__((ext_vector_type(2)));

#define M_ROWS 50000
#define M_PAD  50048
#define M_TILES 391
#define N_REAL 1440     // 3 br * 3 tap * 160 (f padded 150->160)
#define N_PAD  1536
#define N_TILES 12
#define K_DIM  300
#define K_PAD  320
#define KT     10       // K-chunks of 32
#define TROW   1440     // u16 elements per T row (2880 B, 16B-aligned)
#define YCOL   152      // LDS ybuf row width (19 groups * 8)

static __device__ __forceinline__ u16 f2bf(float x){
  union { float f; u32 u; } a; a.f = x;
  u32 r = a.u + 0x7fffu + ((a.u >> 16) & 1u);   // RNE
  return (u16)(r >> 16);
}
static __device__ __forceinline__ u16 f2h(float x){
  _Float16 h = (_Float16)x;
  u16 r; __builtin_memcpy(&r, &h, 2); return r;
}
static __device__ __forceinline__ float h2f(u16 v){
  _Float16 h; __builtin_memcpy(&h, &v, 2); return (float)h;
}

// ---- DPP wave reduction: sum of all 64 lanes lands in lane 63 (6 VALU ops) ----
template<int CTRL>
static __device__ __forceinline__ float dppadd(float x){
  union { float f; int i; } a, b; a.f = x;
  b.i = __builtin_amdgcn_update_dpp(0, a.i, CTRL, 0xf, 0xf, true);
  return x + b.f;
}
static __device__ __forceinline__ float wsum63(float x){
  x = dppadd<0x111>(x);  // row_shr:1
  x = dppadd<0x112>(x);  // row_shr:2
  x = dppadd<0x114>(x);  // row_shr:4
  x = dppadd<0x118>(x);  // row_shr:8
  x = dppadd<0x142>(x);  // row_bcast:15
  x = dppadd<0x143>(x);  // row_bcast:31
  return x;              // lane 63 holds the full sum
}
static __device__ __forceinline__ float rdl63(float x){
  union { float f; int i; } a; a.f = x;
  union { int i; float f; } r; r.i = __builtin_amdgcn_readlane(a.i, 63);
  return r.f;
}

// ---------------- K1a: embedding -> swizzled bf16 A ----------------
__global__ void build_A(const float* __restrict__ emb, u16* __restrict__ A){
  int t = blockIdx.x * 256 + threadIdx.x;
  if (t >= M_PAD * 40) return;
  int m = t / 40, kg = t % 40;
  int k0 = kg * 8;
  int kt = kg >> 2, kgl = kg & 3;
  int tile = m >> 7, ml = m & 127, mb = ml >> 4, row = ml & 15;
  size_t off = ((size_t)tile * KT + kt) * 4096 + mb * 512 + kgl * 128 + row * 8;
  union { uint4 q; u16 s[8]; } p;
  #pragma unroll
  for (int j = 0; j < 8; ++j){
    int k = k0 + j;
    float x = 0.f;
    if (m < M_ROWS && k < K_DIM) x = emb[(size_t)m * K_DIM + k];
    p.s[j] = f2bf(x);
  }
  *(uint4*)(A + off) = p.q;
}

// ---------------- K1b: w1/w2/w3 -> swizzled bf16 B (padded f) --------------------
__global__ void build_B(const float* __restrict__ w1, const float* __restrict__ w2,
                        const float* __restrict__ w3, u16* __restrict__ B){
  int t = blockIdx.x * 256 + threadIdx.x;
  if (t >= N_PAD * K_PAD) return;
  int n = t / K_PAD, k = t % K_PAD;
  float x = 0.f;
  if (n < N_REAL && k < K_DIM){
    int br = n / 480, rem = n % 480, tap = rem / 160, f = rem % 160;
    if (f < 150){
      const float* w = (br == 0) ? w1 : ((br == 1) ? w2 : w3);
      x = w[(tap * K_DIM + k) * 150 + f];
    }
  }
  int tn = n >> 7, nl = n & 127, nb = nl >> 4, col = nl & 15;
  int kt = k >> 5, kl = k & 31, kg = kl >> 3, k8 = kl & 7;
  B[((size_t)tn * KT + kt) * 4096 + nb * 512 + kg * 128 + col * 8 + k8] = f2bf(x);
}

// ---------------- K2: T = A x B^T  (128x128 tile, BK=64: 5 staging rounds) --------
__global__ __launch_bounds__(256) void gemm_k(const u16* __restrict__ A, const u16* __restrict__ B,
                                              u16* __restrict__ T){
  __shared__ __align__(16) u16 lds[16384];   // A: 2x4096 u16 | B: 2x4096 u16 (32 KB)
  const int tm = blockIdx.x, tn = blockIdx.y;
  const int tid = threadIdx.x, wave = tid >> 6, lane = tid & 63;
  f32x4 acc[4][4];
  #pragma unroll
  for (int i = 0; i < 4; ++i)
    #pragma unroll
    for (int j = 0; j < 4; ++j) acc[i][j] = (f32x4){0.f, 0.f, 0.f, 0.f};
  const u16* Ab = A + (size_t)tm * KT * 4096;
  const u16* Bb = B + (size_t)tn * KT * 4096;
  const int mbase = (wave >> 1) * 4;
  const int nbase = (wave & 1) * 4;
  for (int rd = 0; rd < 5; ++rd){
    __syncthreads();
    const u16* ga = Ab + rd * 8192;
    const u16* gb = Bb + rd * 8192;
    #pragma unroll
    for (int j = 0; j < 4; ++j)
      __builtin_amdgcn_global_load_lds((const __attribute__((address_space(1))) void*)(ga + j * 2048 + tid * 8),
                                       (__attribute__((address_space(3))) void*)(lds + j * 2048 + tid * 8), 16, 0, 0);
    #pragma unroll
    for (int j = 0; j < 4; ++j)
      __builtin_amdgcn_global_load_lds((const __attribute__((address_space(1))) void*)(gb + j * 2048 + tid * 8),
                                       (__attribute__((address_space(3))) void*)(lds + 8192 + j * 2048 + tid * 8), 16, 0, 0);
    __syncthreads();
    #pragma unroll
    for (int kk = 0; kk < 2; ++kk){
      const bf16x8* A8 = (const bf16x8*)(lds + kk * 4096);
      const bf16x8* B8 = (const bf16x8*)(lds + 8192 + kk * 4096);
      bf16x8 av[4], bv[4];
      #pragma unroll
      for (int i = 0; i < 4; ++i) av[i] = A8[(mbase + i) * 64 + lane];
      #pragma unroll
      for (int j = 0; j < 4; ++j) bv[j] = B8[(nbase + j) * 64 + lane];
      #pragma unroll
      for (int i = 0; i < 4; ++i)
        #pragma unroll
        for (int j = 0; j < 4; ++j)
          acc[i][j] = __builtin_amdgcn_mfma_f32_16x16x32_bf16(av[i], bv[j], acc[i][j], 0, 0, 0);
    }
  }
  const int r0 = (lane >> 4) * 4, c0 = lane & 15;   // C/D: col=lane&15, row=(lane>>4)*4+reg
  #pragma unroll
  for (int i = 0; i < 4; ++i){
    int m0 = tm * 128 + mbase * 16 + i * 16 + r0;
    #pragma unroll
    for (int j = 0; j < 4; ++j){
      int n0 = tn * 128 + nbase * 16 + j * 16 + c0;
      if (n0 < N_REAL){
        #pragma unroll
        for (int r = 0; r < 4; ++r){
          int m = m0 + r;
          if (m < M_ROWS) T[(size_t)m * TROW + n0] = f2h(acc[i][j][r]);   // T is fp16
        }
      }
    }
  }
}

// ---------------- K3: per-title encoder (word-major, DPP reductions, f16 T) --------
// Phase 0: gather T rows, sum 3 taps with v_pk_add_f16, store packed f16 to LDS.
// Phase 1: per-word LN + level-attn, d in regs, DPP reduces.
// Phase 2: word softmax + output.
__global__ __launch_bounds__(256, 5) void encode_k(
    const int* __restrict__ cand, const int* __restrict__ clk,
    const u16* __restrict__ T,
    const float* __restrict__ b1, const float* __restrict__ b2, const float* __restrict__ b3,
    const float* __restrict__ lng, const float* __restrict__ lnb,
    const float* __restrict__ ql, const float* __restrict__ qw,
    float* __restrict__ rc, float* __restrict__ rh){
  __shared__ __align__(16) u16 ybuf[90][YCOL];   // summed f16 y (27.4 KB)
  __shared__ float tl[30];
  __shared__ float pbuf[4][YCOL];
  __shared__ int words[30];
  const int t = blockIdx.x;
  const int tid = threadIdx.x, wave = tid >> 6, lane = tid & 63;
  const int* wp; float* outp;
  if (t < 320){ wp = cand + t * 30;                outp = rc + t * 150; }
  else        { wp = clk + (size_t)(t - 320) * 30; outp = rh + (size_t)(t - 320) * 150; }
  if (tid < 30) words[tid] = wp[tid];
  __syncthreads();
  const float invs = 0.057735026918962576f;  // 1/sqrt(300)
  const int f0 = lane, f1 = lane + 64, f2 = lane + 128;
  const bool has2 = (f2 < 150);

  // ---- phase 0: gather; 3 taps summed via v_pk_add_f16; raw 16B store to LDS ----
  #pragma unroll
  for (int it = 0; it < 7; ++it){
    int item = tid + it * 256;
    if (item < 1710){
      int p = item / 19, fg = item - p * 19;    // p = l*3+br
      int l = p / 3, br = p - l * 3, dil = br + 1;
      union { uint4 q; h2 h[4]; } s; s.q = (uint4){0u, 0u, 0u, 0u};
      #pragma unroll
      for (int tap = 0; tap < 3; ++tap){
        int ls = l + (tap - 1) * dil;
        if (ls >= 0 && ls < 30){
          union { uint4 q; h2 h[4]; } v;
          v.q = *(const uint4*)(T + (size_t)words[ls] * TROW + br * 480 + tap * 160 + fg * 8);
          #pragma unroll
          for (int i = 0; i < 4; ++i) s.h[i] += v.h[i];   // v_pk_add_f16
        }
      }
      *(uint4*)&ybuf[p][fg * 8] = s.q;
    }
  }

  // preload per-lane params (uniform across words)
  float qlv0 = ql[f0], qlv1 = ql[f1], qlv2 = has2 ? ql[f2] : 0.f;
  float qwv0 = qw[f0], qwv1 = qw[f1], qwv2 = has2 ? qw[f2] : 0.f;
  float lg0 = lng[f0], lg1 = lng[f1], lg2 = has2 ? lng[f2] : 0.f;
  float lb0 = lnb[f0], lb1 = lnb[f1], lb2 = has2 ? lnb[f2] : 0.f;
  float bs[3][3];
  {
    const float* bl[3] = {b1, b2, b3};
    #pragma unroll
    for (int br = 0; br < 3; ++br){
      bs[br][0] = bl[br][f0]; bs[br][1] = bl[br][f1]; bs[br][2] = has2 ? bl[br][f2] : 0.f;
    }
  }
  __syncthreads();

  // ---- phase 1: word-major LN + level-attn (d in regs, DPP reduces) ----
  float at0[8], at1[8], at2[8]; int myl[8]; int nw = 0;
  for (int l = wave; l < 30; l += 4){
    float dr[3][3]; float lvl[3];
    #pragma unroll
    for (int br = 0; br < 3; ++br){
      int p = l * 3 + br;
      float y0 = h2f(ybuf[p][f0]) + bs[br][0];
      float y1 = h2f(ybuf[p][f1]) + bs[br][1];
      float y2 = has2 ? (h2f(ybuf[p][f2]) + bs[br][2]) : 0.f;
      float s  = y0 + y1 + y2;
      float ss = y0 * y0 + y1 * y1 + y2 * y2;
      float st = wsum63(s), sst = wsum63(ss);
      float mean = rdl63(st) * (1.f / 150.f);
      float var  = rdl63(sst) * (1.f / 150.f) - mean * mean;
      float rstd = rsqrtf(var + 1e-5f);
      float d0 = fmaxf((y0 - mean) * rstd * lg0 + lb0, 0.f);
      float d1 = fmaxf((y1 - mean) * rstd * lg1 + lb1, 0.f);
      float d2 = has2 ? fmaxf((y2 - mean) * rstd * lg2 + lb2, 0.f) : 0.f;
      dr[br][0] = d0; dr[br][1] = d1; dr[br][2] = d2;
      float dot = qlv0 * d0 + qlv1 * d1 + qlv2 * d2;
      lvl[br] = rdl63(wsum63(dot)) * invs;
    }
    // wave-local level softmax
    float mx = fmaxf(lvl[0], fmaxf(lvl[1], lvl[2]));
    float e0 = expf(lvl[0] - mx), e1 = expf(lvl[1] - mx), e2 = expf(lvl[2] - mx);
    float inv = 1.f / (e0 + e1 + e2);
    float w0 = e0 * inv, w1v = e1 * inv, w2v = e2 * inv;
    float a0 = w0 * dr[0][0] + w1v * dr[1][0] + w2v * dr[2][0];
    float a1 = w0 * dr[0][1] + w1v * dr[1][1] + w2v * dr[2][1];
    float a2 = w0 * dr[0][2] + w1v * dr[1][2] + w2v * dr[2][2];
    float dot = qwv0 * a0 + qwv1 * a1 + qwv2 * a2;
    float tw = wsum63(dot);
    if (lane == 63) tl[l] = tw * invs;
    at0[nw] = a0; at1[nw] = a1; at2[nw] = a2; myl[nw] = l; ++nw;
  }
  __syncthreads();

  // ---- phase 2: word softmax + per-wave partial reprs ----
  float mx = -1e30f;
  for (int l = 0; l < 30; ++l) mx = fmaxf(mx, tl[l]);
  float den = 0.f;
  for (int l = 0; l < 30; ++l) den += expf(tl[l] - mx);
  float invden = 1.f / den;
  float p0 = 0.f, p1 = 0.f, p2 = 0.f;
  for (int q = 0; q < nw; ++q){
    float wwv = expf(tl[myl[q]] - mx) * invden;
    p0 += wwv * at0[q]; p1 += wwv * at1[q]; p2 += wwv * at2[q];
  }
  pbuf[wave][lane] = p0;
  pbuf[wave][lane + 64] = p1;
  if (has2) pbuf[wave][lane + 128] = p2;
  __syncthreads();
  if (tid < 150) outp[tid] = pbuf[0][tid] + pbuf[1][tid] + pbuf[2][tid] + pbuf[3][tid];
}

// ---------------- K4: scores -> logits -> log_softmax ----------------
__global__ __launch_bounds__(64) void final_k(const float* __restrict__ rc, const float* __restrict__ rh,
                                              const float* __restrict__ lw, const float* __restrict__ lb,
                                              float* __restrict__ out){
  __shared__ float sc[5][50];
  __shared__ float lg[5];
  const int b = blockIdx.x, tid = threadIdx.x;
  const float* C = rc + b * 5 * 150;
  const float* H = rh + (size_t)b * 50 * 150;
  for (int p = tid; p < 250; p += 64){
    int c = p / 50, h = p % 50;
    float s = 0.f;
    for (int k = 0; k < 150; ++k) s += C[c * 150 + k] * H[h * 150 + k];
    sc[c][h] = s;
  }
  __syncthreads();
  if (tid < 5){
    float s = lb[0];
    for (int h = 0; h < 50; ++h) s += sc[tid][h] * lw[h];
    lg[tid] = s;
  }
  __syncthreads();
  if (tid < 5){
    float mx = fmaxf(fmaxf(fmaxf(lg[0], lg[1]), fmaxf(lg[2], lg[3])), lg[4]);
    float den = 0.f;
    for (int c = 0; c < 5; ++c) den += expf(lg[c] - mx);
    out[b * 5 + tid] = lg[tid] - mx - logf(den);
  }
}

extern "C" void kernel_launch(void* const* d_in, const int* in_sizes, int n_in,
                              void* d_out, int out_size, void* d_ws, size_t ws_size,
                              hipStream_t stream){
  const int*   cand = (const int*)d_in[0];
  const int*   clk  = (const int*)d_in[1];
  const float* emb  = (const float*)d_in[2];
  const float* w1   = (const float*)d_in[3];
  const float* b1   = (const float*)d_in[4];
  const float* w2   = (const float*)d_in[5];
  const float* b2   = (const float*)d_in[6];
  const float* w3   = (const float*)d_in[7];
  const float* b3   = (const float*)d_in[8];
  const float* lng  = (const float*)d_in[9];
  const float* lnb  = (const float*)d_in[10];
  const float* ql   = (const float*)d_in[11];
  const float* qw   = (const float*)d_in[12];
  const float* lw   = (const float*)d_in[13];
  const float* lb   = (const float*)d_in[14];
  float* out = (float*)d_out;

  char* ws = (char*)d_ws;
  const size_t szA = (size_t)M_TILES * KT * 8192;   // 32,030,720
  const size_t szB = (size_t)N_TILES * KT * 8192;   //     983,040
  const size_t szT = (size_t)M_ROWS * TROW * 2;     // 144,000,000
  u16*   A  = (u16*)ws;
  u16*   B  = (u16*)(ws + szA);
  u16*   T  = (u16*)(ws + szA + szB);
  float* rc = (float*)(ws + szA + szB + szT);
  float* rh = rc + 320 * 150;

  build_A<<<(M_PAD * 40 + 255) / 256, 256, 0, stream>>>(emb, A);
  build_B<<<(N_PAD * K_PAD + 255) / 256, 256, 0, stream>>>(w1, w2, w3, B);
  gemm_k<<<dim3(M_TILES, N_TILES), 256, 0, stream>>>(A, B, T);
  encode_k<<<3520, 256, 0, stream>>>(cand, clk, T, b1, b2, b3, lng, lnb, ql, qw, rc, rh);
  final_k<<<64, 64, 0, stream>>>(rc, rh, lw, lb, out);
}

// Round 6
// 340.305 us; speedup vs baseline: 2.0175x; 1.0097x over previous
//
#include <hip/hip_runtime.h>

typedef unsigned short u16;
typedef unsigned int   u32;
typedef __bf16 bf16x8 __attribute__((ext_vector_type(8)));
typedef float  f32x4  __attribute__((ext_vector_type(4)));
typedef _Float16 h2 __attribute__((ext_vector_type(2)));

#define M_ROWS 50000
#define M_PAD  50048
#define M_TILES 391
#define N_REAL 1440     // 3 br * 3 tap * 160 (f padded 150->160)
#define N_PAD  1536
#define N_TILES 12
#define K_DIM  300
#define K_PAD  320
#define KT     10       // K-chunks of 32
#define TROW   1440     // u16 elements per T row (2880 B, 16B-aligned)
#define YCOL   152      // LDS ybuf row width (19 groups * 8)

static __device__ __forceinline__ u16 f2bf(float x){
  union { float f; u32 u; } a; a.f = x;
  u32 r = a.u + 0x7fffu + ((a.u >> 16) & 1u);   // RNE
  return (u16)(r >> 16);
}
static __device__ __forceinline__ u16 f2h(float x){
  _Float16 h = (_Float16)x;
  u16 r; __builtin_memcpy(&r, &h, 2); return r;
}
static __device__ __forceinline__ float h2f(u16 v){
  _Float16 h; __builtin_memcpy(&h, &v, 2); return (float)h;
}

// ---- DPP wave reduction: sum of all 64 lanes lands in lane 63 (6 VALU ops) ----
template<int CTRL>
static __device__ __forceinline__ float dppadd(float x){
  union { float f; int i; } a, b; a.f = x;
  b.i = __builtin_amdgcn_update_dpp(0, a.i, CTRL, 0xf, 0xf, true);
  return x + b.f;
}
static __device__ __forceinline__ float wsum63(float x){
  x = dppadd<0x111>(x);  // row_shr:1
  x = dppadd<0x112>(x);  // row_shr:2
  x = dppadd<0x114>(x);  // row_shr:4
  x = dppadd<0x118>(x);  // row_shr:8
  x = dppadd<0x142>(x);  // row_bcast:15
  x = dppadd<0x143>(x);  // row_bcast:31
  return x;              // lane 63 holds the full sum
}
static __device__ __forceinline__ float rdl63(float x){
  union { float f; int i; } a; a.f = x;
  union { int i; float f; } r; r.i = __builtin_amdgcn_readlane(a.i, 63);
  return r.f;
}

// ---------------- K1a: embedding -> swizzled bf16 A ----------------
__global__ void build_A(const float* __restrict__ emb, u16* __restrict__ A){
  int t = blockIdx.x * 256 + threadIdx.x;
  if (t >= M_PAD * 40) return;
  int m = t / 40, kg = t % 40;
  int k0 = kg * 8;
  int kt = kg >> 2, kgl = kg & 3;
  int tile = m >> 7, ml = m & 127, mb = ml >> 4, row = ml & 15;
  size_t off = ((size_t)tile * KT + kt) * 4096 + mb * 512 + kgl * 128 + row * 8;
  union { uint4 q; u16 s[8]; } p;
  #pragma unroll
  for (int j = 0; j < 8; ++j){
    int k = k0 + j;
    float x = 0.f;
    if (m < M_ROWS && k < K_DIM) x = emb[(size_t)m * K_DIM + k];
    p.s[j] = f2bf(x);
  }
  *(uint4*)(A + off) = p.q;
}

// ---------------- K1b: w1/w2/w3 -> swizzled bf16 B (padded f) --------------------
__global__ void build_B(const float* __restrict__ w1, const float* __restrict__ w2,
                        const float* __restrict__ w3, u16* __restrict__ B){
  int t = blockIdx.x * 256 + threadIdx.x;
  if (t >= N_PAD * K_PAD) return;
  int n = t / K_PAD, k = t % K_PAD;
  float x = 0.f;
  if (n < N_REAL && k < K_DIM){
    int br = n / 480, rem = n % 480, tap = rem / 160, f = rem % 160;
    if (f < 150){
      const float* w = (br == 0) ? w1 : ((br == 1) ? w2 : w3);
      x = w[(tap * K_DIM + k) * 150 + f];
    }
  }
  int tn = n >> 7, nl = n & 127, nb = nl >> 4, col = nl & 15;
  int kt = k >> 5, kl = k & 31, kg = kl >> 3, k8 = kl & 7;
  B[((size_t)tn * KT + kt) * 4096 + nb * 512 + kg * 128 + col * 8 + k8] = f2bf(x);
}

// ---------------- K2: T = A x B^T  (128x128 tile, BK=64: 5 staging rounds) --------
__global__ __launch_bounds__(256) void gemm_k(const u16* __restrict__ A, const u16* __restrict__ B,
                                              u16* __restrict__ T){
  __shared__ __align__(16) u16 lds[16384];   // A: 2x4096 u16 | B: 2x4096 u16 (32 KB)
  const int tm = blockIdx.x, tn = blockIdx.y;
  const int tid = threadIdx.x, wave = tid >> 6, lane = tid & 63;
  f32x4 acc[4][4];
  #pragma unroll
  for (int i = 0; i < 4; ++i)
    #pragma unroll
    for (int j = 0; j < 4; ++j) acc[i][j] = (f32x4){0.f, 0.f, 0.f, 0.f};
  const u16* Ab = A + (size_t)tm * KT * 4096;
  const u16* Bb = B + (size_t)tn * KT * 4096;
  const int mbase = (wave >> 1) * 4;
  const int nbase = (wave & 1) * 4;
  for (int rd = 0; rd < 5; ++rd){
    __syncthreads();
    const u16* ga = Ab + rd * 8192;
    const u16* gb = Bb + rd * 8192;
    #pragma unroll
    for (int j = 0; j < 4; ++j)
      __builtin_amdgcn_global_load_lds((const __attribute__((address_space(1))) void*)(ga + j * 2048 + tid * 8),
                                       (__attribute__((address_space(3))) void*)(lds + j * 2048 + tid * 8), 16, 0, 0);
    #pragma unroll
    for (int j = 0; j < 4; ++j)
      __builtin_amdgcn_global_load_lds((const __attribute__((address_space(1))) void*)(gb + j * 2048 + tid * 8),
                                       (__attribute__((address_space(3))) void*)(lds + 8192 + j * 2048 + tid * 8), 16, 0, 0);
    __syncthreads();
    #pragma unroll
    for (int kk = 0; kk < 2; ++kk){
      const bf16x8* A8 = (const bf16x8*)(lds + kk * 4096);
      const bf16x8* B8 = (const bf16x8*)(lds + 8192 + kk * 4096);
      bf16x8 av[4], bv[4];
      #pragma unroll
      for (int i = 0; i < 4; ++i) av[i] = A8[(mbase + i) * 64 + lane];
      #pragma unroll
      for (int j = 0; j < 4; ++j) bv[j] = B8[(nbase + j) * 64 + lane];
      #pragma unroll
      for (int i = 0; i < 4; ++i)
        #pragma unroll
        for (int j = 0; j < 4; ++j)
          acc[i][j] = __builtin_amdgcn_mfma_f32_16x16x32_bf16(av[i], bv[j], acc[i][j], 0, 0, 0);
    }
  }
  const int r0 = (lane >> 4) * 4, c0 = lane & 15;   // C/D: col=lane&15, row=(lane>>4)*4+reg
  #pragma unroll
  for (int i = 0; i < 4; ++i){
    int m0 = tm * 128 + mbase * 16 + i * 16 + r0;
    #pragma unroll
    for (int j = 0; j < 4; ++j){
      int n0 = tn * 128 + nbase * 16 + j * 16 + c0;
      if (n0 < N_REAL){
        #pragma unroll
        for (int r = 0; r < 4; ++r){
          int m = m0 + r;
          if (m < M_ROWS) T[(size_t)m * TROW + n0] = f2h(acc[i][j][r]);   // T is fp16
        }
      }
    }
  }
}

// ---------------- K3: per-title encoder (512 thr, word-major, DPP reductions) ------
// Phase 0: gather T rows, sum 3 taps with v_pk_add_f16, store packed f16 to LDS.
// Phase 1: per-word LN + level-attn, d in regs, DPP reduces (<=4 words/wave).
// Phase 2: word softmax + output.
__global__ __launch_bounds__(512, 8) void encode_k(
    const int* __restrict__ cand, const int* __restrict__ clk,
    const u16* __restrict__ T,
    const float* __restrict__ b1, const float* __restrict__ b2, const float* __restrict__ b3,
    const float* __restrict__ lng, const float* __restrict__ lnb,
    const float* __restrict__ ql, const float* __restrict__ qw,
    float* __restrict__ rc, float* __restrict__ rh){
  __shared__ __align__(16) u16 ybuf[90][YCOL];   // summed f16 y (27.4 KB)
  __shared__ float tl[30];
  __shared__ float pbuf[8][YCOL];
  __shared__ int words[30];
  const int t = blockIdx.x;
  const int tid = threadIdx.x, wave = tid >> 6, lane = tid & 63;
  const int* wp; float* outp;
  if (t < 320){ wp = cand + t * 30;                outp = rc + t * 150; }
  else        { wp = clk + (size_t)(t - 320) * 30; outp = rh + (size_t)(t - 320) * 150; }
  if (tid < 30) words[tid] = wp[tid];
  __syncthreads();
  const float invs = 0.057735026918962576f;  // 1/sqrt(300)
  const int f0 = lane, f1 = lane + 64, f2 = lane + 128;
  const bool has2 = (f2 < 150);

  // ---- phase 0: gather; 3 taps summed via v_pk_add_f16; raw 16B store to LDS ----
  #pragma unroll
  for (int it = 0; it < 4; ++it){
    int item = tid + it * 512;
    if (item < 1710){
      int p = item / 19, fg = item - p * 19;    // p = l*3+br
      int l = p / 3, br = p - l * 3, dil = br + 1;
      union { uint4 q; h2 h[4]; } s; s.q = (uint4){0u, 0u, 0u, 0u};
      #pragma unroll
      for (int tap = 0; tap < 3; ++tap){
        int ls = l + (tap - 1) * dil;
        if (ls >= 0 && ls < 30){
          union { uint4 q; h2 h[4]; } v;
          v.q = *(const uint4*)(T + (size_t)words[ls] * TROW + br * 480 + tap * 160 + fg * 8);
          #pragma unroll
          for (int i = 0; i < 4; ++i) s.h[i] += v.h[i];   // v_pk_add_f16
        }
      }
      *(uint4*)&ybuf[p][fg * 8] = s.q;
    }
  }

  // preload per-lane params (uniform across words)
  float qlv0 = ql[f0], qlv1 = ql[f1], qlv2 = has2 ? ql[f2] : 0.f;
  float qwv0 = qw[f0], qwv1 = qw[f1], qwv2 = has2 ? qw[f2] : 0.f;
  float lg0 = lng[f0], lg1 = lng[f1], lg2 = has2 ? lng[f2] : 0.f;
  float lb0 = lnb[f0], lb1 = lnb[f1], lb2 = has2 ? lnb[f2] : 0.f;
  float bs[3][3];
  {
    const float* bl[3] = {b1, b2, b3};
    #pragma unroll
    for (int br = 0; br < 3; ++br){
      bs[br][0] = bl[br][f0]; bs[br][1] = bl[br][f1]; bs[br][2] = has2 ? bl[br][f2] : 0.f;
    }
  }
  __syncthreads();

  // ---- phase 1: word-major LN + level-attn (d in regs, DPP reduces) ----
  float at0[4], at1[4], at2[4]; int myl[4]; int nw = 0;
  for (int l = wave; l < 30; l += 8){
    float dr[3][3]; float lvl[3];
    #pragma unroll
    for (int br = 0; br < 3; ++br){
      int p = l * 3 + br;
      float y0 = h2f(ybuf[p][f0]) + bs[br][0];
      float y1 = h2f(ybuf[p][f1]) + bs[br][1];
      float y2 = has2 ? (h2f(ybuf[p][f2]) + bs[br][2]) : 0.f;
      float s  = y0 + y1 + y2;
      float ss = y0 * y0 + y1 * y1 + y2 * y2;
      float st = wsum63(s), sst = wsum63(ss);
      float mean = rdl63(st) * (1.f / 150.f);
      float var  = rdl63(sst) * (1.f / 150.f) - mean * mean;
      float rstd = rsqrtf(var + 1e-5f);
      float d0 = fmaxf((y0 - mean) * rstd * lg0 + lb0, 0.f);
      float d1 = fmaxf((y1 - mean) * rstd * lg1 + lb1, 0.f);
      float d2 = has2 ? fmaxf((y2 - mean) * rstd * lg2 + lb2, 0.f) : 0.f;
      dr[br][0] = d0; dr[br][1] = d1; dr[br][2] = d2;
      float dot = qlv0 * d0 + qlv1 * d1 + qlv2 * d2;
      lvl[br] = rdl63(wsum63(dot)) * invs;
    }
    // wave-local level softmax
    float mx = fmaxf(lvl[0], fmaxf(lvl[1], lvl[2]));
    float e0 = expf(lvl[0] - mx), e1 = expf(lvl[1] - mx), e2 = expf(lvl[2] - mx);
    float inv = 1.f / (e0 + e1 + e2);
    float w0 = e0 * inv, w1v = e1 * inv, w2v = e2 * inv;
    float a0 = w0 * dr[0][0] + w1v * dr[1][0] + w2v * dr[2][0];
    float a1 = w0 * dr[0][1] + w1v * dr[1][1] + w2v * dr[2][1];
    float a2 = w0 * dr[0][2] + w1v * dr[1][2] + w2v * dr[2][2];
    float dot = qwv0 * a0 + qwv1 * a1 + qwv2 * a2;
    float tw = wsum63(dot);
    if (lane == 63) tl[l] = tw * invs;
    at0[nw] = a0; at1[nw] = a1; at2[nw] = a2; myl[nw] = l; ++nw;
  }
  __syncthreads();

  // ---- phase 2: word softmax + per-wave partial reprs ----
  float mx = -1e30f;
  for (int l = 0; l < 30; ++l) mx = fmaxf(mx, tl[l]);
  float den = 0.f;
  for (int l = 0; l < 30; ++l) den += expf(tl[l] - mx);
  float invden = 1.f / den;
  float p0 = 0.f, p1 = 0.f, p2 = 0.f;
  for (int q = 0; q < nw; ++q){
    float wwv = expf(tl[myl[q]] - mx) * invden;
    p0 += wwv * at0[q]; p1 += wwv * at1[q]; p2 += wwv * at2[q];
  }
  pbuf[wave][lane] = p0;
  pbuf[wave][lane + 64] = p1;
  if (has2) pbuf[wave][lane + 128] = p2;
  __syncthreads();
  if (tid < 150){
    float acc = 0.f;
    #pragma unroll
    for (int w = 0; w < 8; ++w) acc += pbuf[w][tid];
    outp[tid] = acc;
  }
}

// ---------------- K4: scores -> logits -> log_softmax ----------------
__global__ __launch_bounds__(64) void final_k(const float* __restrict__ rc, const float* __restrict__ rh,
                                              const float* __restrict__ lw, const float* __restrict__ lb,
                                              float* __restrict__ out){
  __shared__ float sc[5][50];
  __shared__ float lg[5];
  const int b = blockIdx.x, tid = threadIdx.x;
  const float* C = rc + b * 5 * 150;
  const float* H = rh + (size_t)b * 50 * 150;
  for (int p = tid; p < 250; p += 64){
    int c = p / 50, h = p % 50;
    float s = 0.f;
    for (int k = 0; k < 150; ++k) s += C[c * 150 + k] * H[h * 150 + k];
    sc[c][h] = s;
  }
  __syncthreads();
  if (tid < 5){
    float s = lb[0];
    for (int h = 0; h < 50; ++h) s += sc[tid][h] * lw[h];
    lg[tid] = s;
  }
  __syncthreads();
  if (tid < 5){
    float mx = fmaxf(fmaxf(fmaxf(lg[0], lg[1]), fmaxf(lg[2], lg[3])), lg[4]);
    float den = 0.f;
    for (int c = 0; c < 5; ++c) den += expf(lg[c] - mx);
    out[b * 5 + tid] = lg[tid] - mx - logf(den);
  }
}

extern "C" void kernel_launch(void* const* d_in, const int* in_sizes, int n_in,
                              void* d_out, int out_size, void* d_ws, size_t ws_size,
                              hipStream_t stream){
  const int*   cand = (const int*)d_in[0];
  const int*   clk  = (const int*)d_in[1];
  const float* emb  = (const float*)d_in[2];
  const float* w1   = (const float*)d_in[3];
  const float* b1   = (const float*)d_in[4];
  const float* w2   = (const float*)d_in[5];
  const float* b2   = (const float*)d_in[6];
  const float* w3   = (const float*)d_in[7];
  const float* b3   = (const float*)d_in[8];
  const float* lng  = (const float*)d_in[9];
  const float* lnb  = (const float*)d_in[10];
  const float* ql   = (const float*)d_in[11];
  const float* qw   = (const float*)d_in[12];
  const float* lw   = (const float*)d_in[13];
  const float* lb   = (const float*)d_in[14];
  float* out = (float*)d_out;

  char* ws = (char*)d_ws;
  const size_t szA = (size_t)M_TILES * KT * 8192;   // 32,030,720
  const size_t szB = (size_t)N_TILES * KT * 8192;   //     983,040
  const size_t szT = (size_t)M_ROWS * TROW * 2;     // 144,000,000
  u16*   A  = (u16*)ws;
  u16*   B  = (u16*)(ws + szA);
  u16*   T  = (u16*)(ws + szA + szB);
  float* rc = (float*)(ws + szA + szB + szT);
  float* rh = rc + 320 * 150;

  build_A<<<(M_PAD * 40 + 255) / 256, 256, 0, stream>>>(emb, A);
  build_B<<<(N_PAD * K_PAD + 255) / 256, 256, 0, stream>>>(w1, w2, w3, B);
  gemm_k<<<dim3(M_TILES, N_TILES), 256, 0, stream>>>(A, B, T);
  encode_k<<<3520, 512, 0, stream>>>(cand, clk, T, b1, b2, b3, lng, lnb, ql, qw, rc, rh);
  final_k<<<64, 64, 0, stream>>>(rc, rh, lw, lb, out);
}

// Round 7
// 336.797 us; speedup vs baseline: 2.0385x; 1.0104x over previous
//
#include <hip/hip_runtime.h>

typedef unsigned short u16;
typedef unsigned int   u32;
typedef __bf16 bf16x8 __attribute__((ext_vector_type(8)));
typedef float  f32x4  __attribute__((ext_vector_type(4)));
typedef _Float16 h2 __attribute__((ext_vector_type(2)));

#define M_ROWS 50000
#define M_PAD  50048
#define M_TILES 782     // 64-row tiles
#define N_REAL 1440     // 3 br * 3 tap * 160 (f padded 150->160)
#define N_PAD  1536
#define K_DIM  300
#define K_PAD  320
#define KT     10       // K-chunks of 32
#define TROW   1440     // u16 elements per T row (2880 B, 16B-aligned)
#define YCOL   152      // LDS ybuf row width (19 groups * 8)

#define GLDS(gp, lp) __builtin_amdgcn_global_load_lds( \
    (const __attribute__((address_space(1))) void*)(gp), \
    (__attribute__((address_space(3))) void*)(lp), 16, 0, 0)

static __device__ __forceinline__ u16 f2bf(float x){
  union { float f; u32 u; } a; a.f = x;
  u32 r = a.u + 0x7fffu + ((a.u >> 16) & 1u);   // RNE
  return (u16)(r >> 16);
}
static __device__ __forceinline__ u16 f2h(float x){
  _Float16 h = (_Float16)x;
  u16 r; __builtin_memcpy(&r, &h, 2); return r;
}
static __device__ __forceinline__ float h2f(u16 v){
  _Float16 h; __builtin_memcpy(&h, &v, 2); return (float)h;
}

// ---- DPP wave reduction: sum of all 64 lanes lands in lane 63 (6 VALU ops) ----
template<int CTRL>
static __device__ __forceinline__ float dppadd(float x){
  union { float f; int i; } a, b; a.f = x;
  b.i = __builtin_amdgcn_update_dpp(0, a.i, CTRL, 0xf, 0xf, true);
  return x + b.f;
}
static __device__ __forceinline__ float wsum63(float x){
  x = dppadd<0x111>(x);  // row_shr:1
  x = dppadd<0x112>(x);  // row_shr:2
  x = dppadd<0x114>(x);  // row_shr:4
  x = dppadd<0x118>(x);  // row_shr:8
  x = dppadd<0x142>(x);  // row_bcast:15
  x = dppadd<0x143>(x);  // row_bcast:31
  return x;              // lane 63 holds the full sum
}
static __device__ __forceinline__ float rdl63(float x){
  union { float f; int i; } a; a.f = x;
  union { int i; float f; } r; r.i = __builtin_amdgcn_readlane(a.i, 63);
  return r.f;
}

// ---------------- K1a: embedding -> swizzled bf16 A (coalesced writes) -----------
// One block per 4KB chunk (tile64, kt). Thread tid -> fragment (mb,kgl,row).
__global__ __launch_bounds__(256) void build_A(const float* __restrict__ emb, u16* __restrict__ A){
  const int bx = blockIdx.x;              // 782*10
  const int tile = bx / 10, kt = bx % 10;
  const int tid = threadIdx.x;
  const int mb = tid >> 6, kgl = (tid >> 4) & 3, row = tid & 15;
  const int m = tile * 64 + mb * 16 + row;
  const int k0 = kt * 32 + kgl * 8;
  union { uint4 q; u16 s[8]; } p;
  if (m < M_ROWS && k0 + 8 <= K_DIM){
    const float4* src = (const float4*)(emb + (size_t)m * K_DIM + k0);
    float4 v0 = src[0], v1 = src[1];
    p.s[0] = f2bf(v0.x); p.s[1] = f2bf(v0.y); p.s[2] = f2bf(v0.z); p.s[3] = f2bf(v0.w);
    p.s[4] = f2bf(v1.x); p.s[5] = f2bf(v1.y); p.s[6] = f2bf(v1.z); p.s[7] = f2bf(v1.w);
  } else {
    #pragma unroll
    for (int j = 0; j < 8; ++j){
      int k = k0 + j;
      float x = (m < M_ROWS && k < K_DIM) ? emb[(size_t)m * K_DIM + k] : 0.f;
      p.s[j] = f2bf(x);
    }
  }
  *(uint4*)(A + (size_t)bx * 2048 + tid * 8) = p.q;
}

// ---------------- K1b: w1/w2/w3 -> swizzled bf16 B (padded f) --------------------
__global__ void build_B(const float* __restrict__ w1, const float* __restrict__ w2,
                        const float* __restrict__ w3, u16* __restrict__ B){
  int t = blockIdx.x * 256 + threadIdx.x;
  if (t >= N_PAD * K_PAD) return;
  int n = t / K_PAD, k = t % K_PAD;
  float x = 0.f;
  if (n < N_REAL && k < K_DIM){
    int br = n / 480, rem = n % 480, tap = rem / 160, f = rem % 160;
    if (f < 150){
      const float* w = (br == 0) ? w1 : ((br == 1) ? w2 : w3);
      x = w[(tap * K_DIM + k) * 150 + f];
    }
  }
  int tn = n >> 7, nl = n & 127, nb = nl >> 4, col = nl & 15;
  int kt = k >> 5, kl = k & 31, kg = kl >> 3, k8 = kl & 7;
  B[((size_t)tn * KT + kt) * 4096 + nb * 512 + kg * 128 + col * 8 + k8] = f2bf(x);
}

// ---------------- K2: T = A x B^T  (A-resident 64-row tile, tn-pair loop) ---------
// A tile (64x320, 40 KB) staged once; B streamed per (tp,rd) via 2x16KB dbuf.
// 4 waves, each computing a 64x64 patch (4x4 MFMA tiles) per tn-pair.
__global__ __launch_bounds__(256, 2) void gemm_k(const u16* __restrict__ A, const u16* __restrict__ B,
                                                 u16* __restrict__ T){
  __shared__ __align__(16) u16 lA[20480];       // 40 KB: A tile, chunk kt*2048 + mb*512 + ...
  __shared__ __align__(16) u16 lB[16384];       // 2 x 16 KB: 256 cols x 32 k per stage
  const int tile = blockIdx.x;
  const int tid = threadIdx.x, w = tid >> 6, lane = tid & 63;
  const u16* Ab = A + (size_t)tile * 20480;
  #pragma unroll
  for (int j = 0; j < 10; ++j)
    GLDS(Ab + j * 2048 + tid * 8, lA + j * 2048 + tid * 8);
  #pragma unroll
  for (int jj = 0; jj < 4; ++jj)
    GLDS(B + (size_t)((jj >> 1) * 10) * 4096 + (jj & 1) * 2048 + tid * 8,
         lB + jj * 2048 + tid * 8);
  const bf16x8* A8 = (const bf16x8*)lA;
  const bf16x8* B8 = (const bf16x8*)lB;
  const int r0 = (lane >> 4) * 4, c0 = lane & 15;   // C/D: col=lane&15, row=(lane>>4)*4+reg
  f32x4 acc[4][4];
  for (int s = 0; s < 60; ++s){
    const int tp = s / 10, rd = s % 10;
    __syncthreads();
    if (s < 59){
      const int s1 = s + 1, tp1 = s1 / 10, rd1 = s1 % 10;
      u16* db = lB + (s1 & 1) * 8192;
      #pragma unroll
      for (int jj = 0; jj < 4; ++jj){
        int tn = tp1 * 2 + (jj >> 1);
        GLDS(B + (size_t)(tn * 10 + rd1) * 4096 + (jj & 1) * 2048 + tid * 8,
             db + jj * 2048 + tid * 8);
      }
    }
    if (rd == 0){
      #pragma unroll
      for (int i = 0; i < 4; ++i)
        #pragma unroll
        for (int j = 0; j < 4; ++j) acc[i][j] = (f32x4){0.f, 0.f, 0.f, 0.f};
    }
    bf16x8 av[4], bv[4];
    const int bb = (s & 1) * 1024;
    #pragma unroll
    for (int i = 0; i < 4; ++i) av[i] = A8[rd * 256 + i * 64 + lane];
    #pragma unroll
    for (int j = 0; j < 4; ++j) bv[j] = B8[bb + (w * 4 + j) * 64 + lane];
    #pragma unroll
    for (int i = 0; i < 4; ++i)
      #pragma unroll
      for (int j = 0; j < 4; ++j)
        acc[i][j] = __builtin_amdgcn_mfma_f32_16x16x32_bf16(av[i], bv[j], acc[i][j], 0, 0, 0);
    if (rd == 9){
      #pragma unroll
      for (int i = 0; i < 4; ++i){
        int m0 = tile * 64 + i * 16 + r0;
        #pragma unroll
        for (int j = 0; j < 4; ++j){
          int n0 = tp * 256 + (w * 4 + j) * 16 + c0;
          if (n0 < N_REAL){
            #pragma unroll
            for (int r = 0; r < 4; ++r){
              int m = m0 + r;
              if (m < M_ROWS) T[(size_t)m * TROW + n0] = f2h(acc[i][j][r]);
            }
          }
        }
      }
    }
  }
}

// ---------------- K3: per-title encoder (512 thr, word-major, DPP reductions) ------
__global__ __launch_bounds__(512, 8) void encode_k(
    const int* __restrict__ cand, const int* __restrict__ clk,
    const u16* __restrict__ T,
    const float* __restrict__ b1, const float* __restrict__ b2, const float* __restrict__ b3,
    const float* __restrict__ lng, const float* __restrict__ lnb,
    const float* __restrict__ ql, const float* __restrict__ qw,
    float* __restrict__ rc, float* __restrict__ rh){
  __shared__ __align__(16) u16 ybuf[90][YCOL];   // summed f16 y (27.4 KB)
  __shared__ float tl[30];
  __shared__ float pbuf[8][YCOL];
  __shared__ int words[30];
  const int t = blockIdx.x;
  const int tid = threadIdx.x, wave = tid >> 6, lane = tid & 63;
  const int* wp; float* outp;
  if (t < 320){ wp = cand + t * 30;                outp = rc + t * 150; }
  else        { wp = clk + (size_t)(t - 320) * 30; outp = rh + (size_t)(t - 320) * 150; }
  if (tid < 30) words[tid] = wp[tid];
  __syncthreads();
  const float invs = 0.057735026918962576f;  // 1/sqrt(300)
  const int f0 = lane, f1 = lane + 64, f2 = lane + 128;
  const bool has2 = (f2 < 150);

  // ---- phase 0: gather; 3 taps summed via v_pk_add_f16; raw 16B store to LDS ----
  #pragma unroll
  for (int it = 0; it < 4; ++it){
    int item = tid + it * 512;
    if (item < 1710){
      int p = item / 19, fg = item - p * 19;    // p = l*3+br
      int l = p / 3, br = p - l * 3, dil = br + 1;
      union { uint4 q; h2 h[4]; } s; s.q = (uint4){0u, 0u, 0u, 0u};
      #pragma unroll
      for (int tap = 0; tap < 3; ++tap){
        int ls = l + (tap - 1) * dil;
        if (ls >= 0 && ls < 30){
          union { uint4 q; h2 h[4]; } v;
          v.q = *(const uint4*)(T + (size_t)words[ls] * TROW + br * 480 + tap * 160 + fg * 8);
          #pragma unroll
          for (int i = 0; i < 4; ++i) s.h[i] += v.h[i];   // v_pk_add_f16
        }
      }
      *(uint4*)&ybuf[p][fg * 8] = s.q;
    }
  }

  // preload per-lane params (uniform across words)
  float qlv0 = ql[f0], qlv1 = ql[f1], qlv2 = has2 ? ql[f2] : 0.f;
  float qwv0 = qw[f0], qwv1 = qw[f1], qwv2 = has2 ? qw[f2] : 0.f;
  float lg0 = lng[f0], lg1 = lng[f1], lg2 = has2 ? lng[f2] : 0.f;
  float lb0 = lnb[f0], lb1 = lnb[f1], lb2 = has2 ? lnb[f2] : 0.f;
  float bs[3][3];
  {
    const float* bl[3] = {b1, b2, b3};
    #pragma unroll
    for (int br = 0; br < 3; ++br){
      bs[br][0] = bl[br][f0]; bs[br][1] = bl[br][f1]; bs[br][2] = has2 ? bl[br][f2] : 0.f;
    }
  }
  __syncthreads();

  // ---- phase 1: word-major LN + level-attn (d in regs, DPP reduces) ----
  float at0[4], at1[4], at2[4]; int myl[4]; int nw = 0;
  for (int l = wave; l < 30; l += 8){
    float dr[3][3]; float lvl[3];
    #pragma unroll
    for (int br = 0; br < 3; ++br){
      int p = l * 3 + br;
      float y0 = h2f(ybuf[p][f0]) + bs[br][0];
      float y1 = h2f(ybuf[p][f1]) + bs[br][1];
      float y2 = has2 ? (h2f(ybuf[p][f2]) + bs[br][2]) : 0.f;
      float s  = y0 + y1 + y2;
      float ss = y0 * y0 + y1 * y1 + y2 * y2;
      float st = wsum63(s), sst = wsum63(ss);
      float mean = rdl63(st) * (1.f / 150.f);
      float var  = rdl63(sst) * (1.f / 150.f) - mean * mean;
      float rstd = rsqrtf(var + 1e-5f);
      float d0 = fmaxf((y0 - mean) * rstd * lg0 + lb0, 0.f);
      float d1 = fmaxf((y1 - mean) * rstd * lg1 + lb1, 0.f);
      float d2 = has2 ? fmaxf((y2 - mean) * rstd * lg2 + lb2, 0.f) : 0.f;
      dr[br][0] = d0; dr[br][1] = d1; dr[br][2] = d2;
      float dot = qlv0 * d0 + qlv1 * d1 + qlv2 * d2;
      lvl[br] = rdl63(wsum63(dot)) * invs;
    }
    // wave-local level softmax
    float mx = fmaxf(lvl[0], fmaxf(lvl[1], lvl[2]));
    float e0 = expf(lvl[0] - mx), e1 = expf(lvl[1] - mx), e2 = expf(lvl[2] - mx);
    float inv = 1.f / (e0 + e1 + e2);
    float w0 = e0 * inv, w1v = e1 * inv, w2v = e2 * inv;
    float a0 = w0 * dr[0][0] + w1v * dr[1][0] + w2v * dr[2][0];
    float a1 = w0 * dr[0][1] + w1v * dr[1][1] + w2v * dr[2][1];
    float a2 = w0 * dr[0][2] + w1v * dr[1][2] + w2v * dr[2][2];
    float dot = qwv0 * a0 + qwv1 * a1 + qwv2 * a2;
    float tw = wsum63(dot);
    if (lane == 63) tl[l] = tw * invs;
    at0[nw] = a0; at1[nw] = a1; at2[nw] = a2; myl[nw] = l; ++nw;
  }
  __syncthreads();

  // ---- phase 2: word softmax + per-wave partial reprs ----
  float mx = -1e30f;
  for (int l = 0; l < 30; ++l) mx = fmaxf(mx, tl[l]);
  float den = 0.f;
  for (int l = 0; l < 30; ++l) den += expf(tl[l] - mx);
  float invden = 1.f / den;
  float p0 = 0.f, p1 = 0.f, p2 = 0.f;
  for (int q = 0; q < nw; ++q){
    float wwv = expf(tl[myl[q]] - mx) * invden;
    p0 += wwv * at0[q]; p1 += wwv * at1[q]; p2 += wwv * at2[q];
  }
  pbuf[wave][lane] = p0;
  pbuf[wave][lane + 64] = p1;
  if (has2) pbuf[wave][lane + 128] = p2;
  __syncthreads();
  if (tid < 150){
    float acc = 0.f;
    #pragma unroll
    for (int w = 0; w < 8; ++w) acc += pbuf[w][tid];
    outp[tid] = acc;
  }
}

// ---------------- K4: scores -> logits -> log_softmax (LDS-staged) ----------------
__global__ __launch_bounds__(256) void final_k(const float* __restrict__ rc, const float* __restrict__ rh,
                                               const float* __restrict__ lw, const float* __restrict__ lb,
                                               float* __restrict__ out){
  __shared__ float Cl[750];
  __shared__ float Hl[7500];
  __shared__ float sc[5][52];
  __shared__ float lg[5];
  const int b = blockIdx.x, tid = threadIdx.x;
  const float* C = rc + b * 750;
  const float* H = rh + (size_t)b * 7500;
  for (int i = tid; i < 750; i += 256) Cl[i] = C[i];
  for (int i = tid; i < 7500; i += 256) Hl[i] = H[i];
  __syncthreads();
  if (tid < 250){
    int c = tid / 50, h = tid % 50;
    float s = 0.f;
    #pragma unroll 10
    for (int k = 0; k < 150; ++k) s += Cl[c * 150 + k] * Hl[h * 150 + k];
    sc[c][h] = s;
  }
  __syncthreads();
  if (tid < 5){
    float s = lb[0];
    for (int h = 0; h < 50; ++h) s += sc[tid][h] * lw[h];
    lg[tid] = s;
  }
  __syncthreads();
  if (tid < 5){
    float mx = fmaxf(fmaxf(fmaxf(lg[0], lg[1]), fmaxf(lg[2], lg[3])), lg[4]);
    float den = 0.f;
    for (int c = 0; c < 5; ++c) den += expf(lg[c] - mx);
    out[b * 5 + tid] = lg[tid] - mx - logf(den);
  }
}

extern "C" void kernel_launch(void* const* d_in, const int* in_sizes, int n_in,
                              void* d_out, int out_size, void* d_ws, size_t ws_size,
                              hipStream_t stream){
  const int*   cand = (const int*)d_in[0];
  const int*   clk  = (const int*)d_in[1];
  const float* emb  = (const float*)d_in[2];
  const float* w1   = (const float*)d_in[3];
  const float* b1   = (const float*)d_in[4];
  const float* w2   = (const float*)d_in[5];
  const float* b2   = (const float*)d_in[6];
  const float* w3   = (const float*)d_in[7];
  const float* b3   = (const float*)d_in[8];
  const float* lng  = (const float*)d_in[9];
  const float* lnb  = (const float*)d_in[10];
  const float* ql   = (const float*)d_in[11];
  const float* qw   = (const float*)d_in[12];
  const float* lw   = (const float*)d_in[13];
  const float* lb   = (const float*)d_in[14];
  float* out = (float*)d_out;

  char* ws = (char*)d_ws;
  const size_t szA = (size_t)M_TILES * KT * 4096;   // 32,030,720 B (782 x 40 KB)
  const size_t szB = (size_t)12 * KT * 8192;        //     983,040 B
  const size_t szT = (size_t)M_ROWS * TROW * 2;     // 144,000,000 B
  u16*   A  = (u16*)ws;
  u16*   B  = (u16*)(ws + szA);
  u16*   T  = (u16*)(ws + szA + szB);
  float* rc = (float*)(ws + szA + szB + szT);
  float* rh = rc + 320 * 150;

  build_A<<<M_TILES * KT, 256, 0, stream>>>(emb, A);
  build_B<<<(N_PAD * K_PAD + 255) / 256, 256, 0, stream>>>(w1, w2, w3, B);
  gemm_k<<<M_TILES, 256, 0, stream>>>(A, B, T);
  encode_k<<<3520, 512, 0, stream>>>(cand, clk, T, b1, b2, b3, lng, lnb, ql, qw, rc, rh);
  final_k<<<64, 256, 0, stream>>>(rc, rh, lw, lb, out);
}

// Round 8
// 316.803 us; speedup vs baseline: 2.1671x; 1.0631x over previous
//
#include <hip/hip_runtime.h>

typedef unsigned short u16;
typedef unsigned int   u32;
typedef __bf16 bf16x8 __attribute__((ext_vector_type(8)));
typedef float  f32x4  __attribute__((ext_vector_type(4)));
typedef _Float16 h2 __attribute__((ext_vector_type(2)));

#define M_ROWS 50000
#define M_PAD  50048
#define M_TILES 391     // 128-row tiles
#define N_REAL 1440     // 3 br * 3 tap * 160 (f padded 150->160)
#define N_PAD  1536
#define N_TILES 12      // 128-col tiles
#define K_DIM  300
#define K_PAD  320
#define KT     10       // K-chunks of 32
#define TROW   1440     // u16 elements per T row (2880 B, 16B-aligned)
#define YCOL   152      // LDS ybuf row width (19 groups * 8)

#define GLDS(gp, lp) __builtin_amdgcn_global_load_lds( \
    (const __attribute__((address_space(1))) void*)(gp), \
    (__attribute__((address_space(3))) void*)(lp), 16, 0, 0)

static __device__ __forceinline__ u16 f2bf(float x){
  union { float f; u32 u; } a; a.f = x;
  u32 r = a.u + 0x7fffu + ((a.u >> 16) & 1u);   // RNE
  return (u16)(r >> 16);
}
static __device__ __forceinline__ u16 f2h(float x){
  _Float16 h = (_Float16)x;
  u16 r; __builtin_memcpy(&r, &h, 2); return r;
}
static __device__ __forceinline__ float h2f(u16 v){
  _Float16 h; __builtin_memcpy(&h, &v, 2); return (float)h;
}

// ---- DPP wave reduction: sum of all 64 lanes lands in lane 63 (6 VALU ops) ----
template<int CTRL>
static __device__ __forceinline__ float dppadd(float x){
  union { float f; int i; } a, b; a.f = x;
  b.i = __builtin_amdgcn_update_dpp(0, a.i, CTRL, 0xf, 0xf, true);
  return x + b.f;
}
static __device__ __forceinline__ float wsum63(float x){
  x = dppadd<0x111>(x);  // row_shr:1
  x = dppadd<0x112>(x);  // row_shr:2
  x = dppadd<0x114>(x);  // row_shr:4
  x = dppadd<0x118>(x);  // row_shr:8
  x = dppadd<0x142>(x);  // row_bcast:15
  x = dppadd<0x143>(x);  // row_bcast:31
  return x;              // lane 63 holds the full sum
}
static __device__ __forceinline__ float rdl63(float x){
  union { float f; int i; } a; a.f = x;
  union { int i; float f; } r; r.i = __builtin_amdgcn_readlane(a.i, 63);
  return r.f;
}

// ---------------- K1a: embedding -> swizzled bf16 A (coalesced reads) ------------
// 128-row tiles: A u16 offset = (tile*10+kt)*4096 + mb*512 + kgl*128 + row*8 + k8.
// 40 consecutive tids stream one emb row (coalesced 1200 B reads).
__global__ __launch_bounds__(256) void build_A(const float* __restrict__ emb, u16* __restrict__ A){
  int t = blockIdx.x * 256 + threadIdx.x;
  if (t >= M_PAD * 40) return;
  int m = t / 40, kg = t % 40;
  int k0 = kg * 8;
  int kt = kg >> 2, kgl = kg & 3;
  int tile = m >> 7, ml = m & 127, mb = ml >> 4, row = ml & 15;
  size_t off = ((size_t)tile * KT + kt) * 4096 + mb * 512 + kgl * 128 + row * 8;
  union { uint4 q; u16 s[8]; } p;
  if (m < M_ROWS && k0 + 8 <= K_DIM){
    const float4* src = (const float4*)(emb + (size_t)m * K_DIM + k0);
    float4 v0 = src[0], v1 = src[1];
    p.s[0] = f2bf(v0.x); p.s[1] = f2bf(v0.y); p.s[2] = f2bf(v0.z); p.s[3] = f2bf(v0.w);
    p.s[4] = f2bf(v1.x); p.s[5] = f2bf(v1.y); p.s[6] = f2bf(v1.z); p.s[7] = f2bf(v1.w);
  } else {
    #pragma unroll
    for (int j = 0; j < 8; ++j){
      int k = k0 + j;
      float x = (m < M_ROWS && k < K_DIM) ? emb[(size_t)m * K_DIM + k] : 0.f;
      p.s[j] = f2bf(x);
    }
  }
  *(uint4*)(A + off) = p.q;
}

// ---------------- K1b: w1/w2/w3 -> swizzled bf16 B (padded f) --------------------
__global__ void build_B(const float* __restrict__ w1, const float* __restrict__ w2,
                        const float* __restrict__ w3, u16* __restrict__ B){
  int t = blockIdx.x * 256 + threadIdx.x;
  if (t >= N_PAD * K_PAD) return;
  int n = t / K_PAD, k = t % K_PAD;
  float x = 0.f;
  if (n < N_REAL && k < K_DIM){
    int br = n / 480, rem = n % 480, tap = rem / 160, f = rem % 160;
    if (f < 150){
      const float* w = (br == 0) ? w1 : ((br == 1) ? w2 : w3);
      x = w[(tap * K_DIM + k) * 150 + f];
    }
  }
  int tn = n >> 7, nl = n & 127, nb = nl >> 4, col = nl & 15;
  int kt = k >> 5, kl = k & 31, kg = kl >> 3, k8 = kl & 7;
  B[((size_t)tn * KT + kt) * 4096 + nb * 512 + kg * 128 + col * 8 + k8] = f2bf(x);
}

// ---------------- K2: T = A x B^T  (m97 geometry: 128x128 tile, BK=32, 4692 blk) --
// 16 KB LDS -> 5 blocks/CU resident (VGPR-capped), 18.3 blocks/CU total: no tail.
__global__ __launch_bounds__(256) void gemm_k(const u16* __restrict__ A, const u16* __restrict__ B,
                                              u16* __restrict__ T){
  __shared__ __align__(16) u16 lds[8192];   // A tile 8KB | B tile 8KB
  const int tn = blockIdx.x, tm = blockIdx.y;
  const int tid = threadIdx.x, wave = tid >> 6, lane = tid & 63;
  f32x4 acc[4][4];
  #pragma unroll
  for (int i = 0; i < 4; ++i)
    #pragma unroll
    for (int j = 0; j < 4; ++j) acc[i][j] = (f32x4){0.f, 0.f, 0.f, 0.f};
  const u16* Ab = A + (size_t)tm * KT * 4096;
  const u16* Bb = B + (size_t)tn * KT * 4096;
  const int mbase = (wave >> 1) * 4;
  const int nbase = (wave & 1) * 4;
  for (int kt = 0; kt < KT; ++kt){
    __syncthreads();
    const u16* ga = Ab + kt * 4096;
    const u16* gb = Bb + kt * 4096;
    GLDS(ga + tid * 8,        lds + tid * 8);
    GLDS(ga + 2048 + tid * 8, lds + 2048 + tid * 8);
    GLDS(gb + tid * 8,        lds + 4096 + tid * 8);
    GLDS(gb + 2048 + tid * 8, lds + 6144 + tid * 8);
    __syncthreads();
    const bf16x8* A8 = (const bf16x8*)lds;
    const bf16x8* B8 = (const bf16x8*)(lds + 4096);
    bf16x8 av[4], bv[4];
    #pragma unroll
    for (int i = 0; i < 4; ++i) av[i] = A8[(mbase + i) * 64 + lane];
    #pragma unroll
    for (int j = 0; j < 4; ++j) bv[j] = B8[(nbase + j) * 64 + lane];
    #pragma unroll
    for (int i = 0; i < 4; ++i)
      #pragma unroll
      for (int j = 0; j < 4; ++j)
        acc[i][j] = __builtin_amdgcn_mfma_f32_16x16x32_bf16(av[i], bv[j], acc[i][j], 0, 0, 0);
  }
  const int r0 = (lane >> 4) * 4, c0 = lane & 15;   // C/D: col=lane&15, row=(lane>>4)*4+reg
  #pragma unroll
  for (int i = 0; i < 4; ++i){
    int m0 = tm * 128 + mbase * 16 + i * 16 + r0;
    #pragma unroll
    for (int j = 0; j < 4; ++j){
      int n0 = tn * 128 + nbase * 16 + j * 16 + c0;
      if (n0 < N_REAL){
        #pragma unroll
        for (int r = 0; r < 4; ++r){
          int m = m0 + r;
          if (m < M_ROWS) T[(size_t)m * TROW + n0] = f2h(acc[i][j][r]);   // T is fp16
        }
      }
    }
  }
}

// ---------------- K3: per-title encoder (512 thr, word-major, DPP reductions) ------
__global__ __launch_bounds__(512, 8) void encode_k(
    const int* __restrict__ cand, const int* __restrict__ clk,
    const u16* __restrict__ T,
    const float* __restrict__ b1, const float* __restrict__ b2, const float* __restrict__ b3,
    const float* __restrict__ lng, const float* __restrict__ lnb,
    const float* __restrict__ ql, const float* __restrict__ qw,
    float* __restrict__ rc, float* __restrict__ rh){
  __shared__ __align__(16) u16 ybuf[90][YCOL];   // summed f16 y (27.4 KB)
  __shared__ float tl[30];
  __shared__ float pbuf[8][YCOL];
  __shared__ int words[30];
  const int t = blockIdx.x;
  const int tid = threadIdx.x, wave = tid >> 6, lane = tid & 63;
  const int* wp; float* outp;
  if (t < 320){ wp = cand + t * 30;                outp = rc + t * 150; }
  else        { wp = clk + (size_t)(t - 320) * 30; outp = rh + (size_t)(t - 320) * 150; }
  if (tid < 30) words[tid] = wp[tid];
  __syncthreads();
  const float invs = 0.057735026918962576f;  // 1/sqrt(300)
  const int f0 = lane, f1 = lane + 64, f2 = lane + 128;
  const bool has2 = (f2 < 150);

  // ---- phase 0: gather; 3 taps summed via v_pk_add_f16; raw 16B store to LDS ----
  #pragma unroll
  for (int it = 0; it < 4; ++it){
    int item = tid + it * 512;
    if (item < 1710){
      int p = item / 19, fg = item - p * 19;    // p = l*3+br
      int l = p / 3, br = p - l * 3, dil = br + 1;
      union { uint4 q; h2 h[4]; } s; s.q = (uint4){0u, 0u, 0u, 0u};
      #pragma unroll
      for (int tap = 0; tap < 3; ++tap){
        int ls = l + (tap - 1) * dil;
        if (ls >= 0 && ls < 30){
          union { uint4 q; h2 h[4]; } v;
          v.q = *(const uint4*)(T + (size_t)words[ls] * TROW + br * 480 + tap * 160 + fg * 8);
          #pragma unroll
          for (int i = 0; i < 4; ++i) s.h[i] += v.h[i];   // v_pk_add_f16
        }
      }
      *(uint4*)&ybuf[p][fg * 8] = s.q;
    }
  }

  // preload per-lane params (uniform across words)
  float qlv0 = ql[f0], qlv1 = ql[f1], qlv2 = has2 ? ql[f2] : 0.f;
  float qwv0 = qw[f0], qwv1 = qw[f1], qwv2 = has2 ? qw[f2] : 0.f;
  float lg0 = lng[f0], lg1 = lng[f1], lg2 = has2 ? lng[f2] : 0.f;
  float lb0 = lnb[f0], lb1 = lnb[f1], lb2 = has2 ? lnb[f2] : 0.f;
  float bs[3][3];
  {
    const float* bl[3] = {b1, b2, b3};
    #pragma unroll
    for (int br = 0; br < 3; ++br){
      bs[br][0] = bl[br][f0]; bs[br][1] = bl[br][f1]; bs[br][2] = has2 ? bl[br][f2] : 0.f;
    }
  }
  __syncthreads();

  // ---- phase 1: word-major LN + level-attn (d in regs, DPP reduces) ----
  float at0[4], at1[4], at2[4]; int myl[4]; int nw = 0;
  for (int l = wave; l < 30; l += 8){
    float dr[3][3]; float lvl[3];
    #pragma unroll
    for (int br = 0; br < 3; ++br){
      int p = l * 3 + br;
      float y0 = h2f(ybuf[p][f0]) + bs[br][0];
      float y1 = h2f(ybuf[p][f1]) + bs[br][1];
      float y2 = has2 ? (h2f(ybuf[p][f2]) + bs[br][2]) : 0.f;
      float s  = y0 + y1 + y2;
      float ss = y0 * y0 + y1 * y1 + y2 * y2;
      float st = wsum63(s), sst = wsum63(ss);
      float mean = rdl63(st) * (1.f / 150.f);
      float var  = rdl63(sst) * (1.f / 150.f) - mean * mean;
      float rstd = rsqrtf(var + 1e-5f);
      float d0 = fmaxf((y0 - mean) * rstd * lg0 + lb0, 0.f);
      float d1 = fmaxf((y1 - mean) * rstd * lg1 + lb1, 0.f);
      float d2 = has2 ? fmaxf((y2 - mean) * rstd * lg2 + lb2, 0.f) : 0.f;
      dr[br][0] = d0; dr[br][1] = d1; dr[br][2] = d2;
      float dot = qlv0 * d0 + qlv1 * d1 + qlv2 * d2;
      lvl[br] = rdl63(wsum63(dot)) * invs;
    }
    // wave-local level softmax
    float mx = fmaxf(lvl[0], fmaxf(lvl[1], lvl[2]));
    float e0 = expf(lvl[0] - mx), e1 = expf(lvl[1] - mx), e2 = expf(lvl[2] - mx);
    float inv = 1.f / (e0 + e1 + e2);
    float w0 = e0 * inv, w1v = e1 * inv, w2v = e2 * inv;
    float a0 = w0 * dr[0][0] + w1v * dr[1][0] + w2v * dr[2][0];
    float a1 = w0 * dr[0][1] + w1v * dr[1][1] + w2v * dr[2][1];
    float a2 = w0 * dr[0][2] + w1v * dr[1][2] + w2v * dr[2][2];
    float dot = qwv0 * a0 + qwv1 * a1 + qwv2 * a2;
    float tw = wsum63(dot);
    if (lane == 63) tl[l] = tw * invs;
    at0[nw] = a0; at1[nw] = a1; at2[nw] = a2; myl[nw] = l; ++nw;
  }
  __syncthreads();

  // ---- phase 2: word softmax + per-wave partial reprs ----
  float mx = -1e30f;
  for (int l = 0; l < 30; ++l) mx = fmaxf(mx, tl[l]);
  float den = 0.f;
  for (int l = 0; l < 30; ++l) den += expf(tl[l] - mx);
  float invden = 1.f / den;
  float p0 = 0.f, p1 = 0.f, p2 = 0.f;
  for (int q = 0; q < nw; ++q){
    float wwv = expf(tl[myl[q]] - mx) * invden;
    p0 += wwv * at0[q]; p1 += wwv * at1[q]; p2 += wwv * at2[q];
  }
  pbuf[wave][lane] = p0;
  pbuf[wave][lane + 64] = p1;
  if (has2) pbuf[wave][lane + 128] = p2;
  __syncthreads();
  if (tid < 150){
    float acc = 0.f;
    #pragma unroll
    for (int w = 0; w < 8; ++w) acc += pbuf[w][tid];
    outp[tid] = acc;
  }
}

// ---------------- K4: scores -> logits -> log_softmax (LDS-staged) ----------------
__global__ __launch_bounds__(256) void final_k(const float* __restrict__ rc, const float* __restrict__ rh,
                                               const float* __restrict__ lw, const float* __restrict__ lb,
                                               float* __restrict__ out){
  __shared__ float Cl[750];
  __shared__ float Hl[7500];
  __shared__ float sc[5][52];
  __shared__ float lg[5];
  const int b = blockIdx.x, tid = threadIdx.x;
  const float* C = rc + b * 750;
  const float* H = rh + (size_t)b * 7500;
  for (int i = tid; i < 750; i += 256) Cl[i] = C[i];
  for (int i = tid; i < 7500; i += 256) Hl[i] = H[i];
  __syncthreads();
  if (tid < 250){
    int c = tid / 50, h = tid % 50;
    float s = 0.f;
    #pragma unroll 10
    for (int k = 0; k < 150; ++k) s += Cl[c * 150 + k] * Hl[h * 150 + k];
    sc[c][h] = s;
  }
  __syncthreads();
  if (tid < 5){
    float s = lb[0];
    for (int h = 0; h < 50; ++h) s += sc[tid][h] * lw[h];
    lg[tid] = s;
  }
  __syncthreads();
  if (tid < 5){
    float mx = fmaxf(fmaxf(fmaxf(lg[0], lg[1]), fmaxf(lg[2], lg[3])), lg[4]);
    float den = 0.f;
    for (int c = 0; c < 5; ++c) den += expf(lg[c] - mx);
    out[b * 5 + tid] = lg[tid] - mx - logf(den);
  }
}

extern "C" void kernel_launch(void* const* d_in, const int* in_sizes, int n_in,
                              void* d_out, int out_size, void* d_ws, size_t ws_size,
                              hipStream_t stream){
  const int*   cand = (const int*)d_in[0];
  const int*   clk  = (const int*)d_in[1];
  const float* emb  = (const float*)d_in[2];
  const float* w1   = (const float*)d_in[3];
  const float* b1   = (const float*)d_in[4];
  const float* w2   = (const float*)d_in[5];
  const float* b2   = (const float*)d_in[6];
  const float* w3   = (const float*)d_in[7];
  const float* b3   = (const float*)d_in[8];
  const float* lng  = (const float*)d_in[9];
  const float* lnb  = (const float*)d_in[10];
  const float* ql   = (const float*)d_in[11];
  const float* qw   = (const float*)d_in[12];
  const float* lw   = (const float*)d_in[13];
  const float* lb   = (const float*)d_in[14];
  float* out = (float*)d_out;

  char* ws = (char*)d_ws;
  const size_t szA = (size_t)M_TILES * KT * 8192;   // 32,030,720 B
  const size_t szB = (size_t)N_TILES * KT * 8192;   //     983,040 B
  const size_t szT = (size_t)M_ROWS * TROW * 2;     // 144,000,000 B
  u16*   A  = (u16*)ws;
  u16*   B  = (u16*)(ws + szA);
  u16*   T  = (u16*)(ws + szA + szB);
  float* rc = (float*)(ws + szA + szB + szT);
  float* rh = rc + 320 * 150;

  build_A<<<(M_PAD * 40 + 255) / 256, 256, 0, stream>>>(emb, A);
  build_B<<<(N_PAD * K_PAD + 255) / 256, 256, 0, stream>>>(w1, w2, w3, B);
  gemm_k<<<dim3(N_TILES, M_TILES), 256, 0, stream>>>(A, B, T);
  encode_k<<<3520, 512, 0, stream>>>(cand, clk, T, b1, b2, b3, lng, lnb, ql, qw, rc, rh);
  final_k<<<64, 256, 0, stream>>>(rc, rh, lw, lb, out);
}